// Round 1
// baseline (2071.332 us; speedup 1.0000x reference)
//
#include <hip/hip_runtime.h>

// GHM_68143951118654 — bf16 MFMA implementation, v1.
// Pipeline (per block): FF1(+dual gelu out) -> wA -> wB -> S=Hf^T@Wt (partials+reduce,gelu)
//                       -> fused [P=gelu(Wt@agg^T) | gelu(Hf)] @ ff2 + b
// Then colsum/mean + head. edge_index is unused by the reference.

typedef unsigned short u16;
typedef short bf16x8 __attribute__((ext_vector_type(8)));
typedef float f32x4 __attribute__((ext_vector_type(4)));

__device__ __forceinline__ float gelu_f(float x) {
  return 0.5f * x * (1.0f + erff(x * 0.70710678118654752440f));
}
__device__ __forceinline__ u16 f2b(float f) {
  union { float f; unsigned u; } v; v.f = f;
  unsigned u = v.u;
  u += 0x7fffu + ((u >> 16) & 1u);   // round-to-nearest-even
  return (u16)(u >> 16);
}
__device__ __forceinline__ float b2f(u16 h) {
  union { unsigned u; float f; } v; v.u = ((unsigned)h) << 16;
  return v.f;
}

// ---------------------------------------------------------------------------
// Weight prep: fp32 -> bf16, transposed to [out][in] so MFMA B-frags read
// contiguous 16B along k. Concatenated into one ws region, fixed offsets.
// seg sizes (elements): 65536,65536,16384,131072  x2 blocks = 557056 total
// ---------------------------------------------------------------------------
__global__ __launch_bounds__(256) void prep_weights(
    const float* __restrict__ s0, const float* __restrict__ s1,
    const float* __restrict__ s2, const float* __restrict__ s3,
    const float* __restrict__ s4, const float* __restrict__ s5,
    const float* __restrict__ s6, const float* __restrict__ s7,
    u16* __restrict__ dst)
{
  int idx = blockIdx.x * 256 + threadIdx.x;
  if (idx >= 557056) return;
  const float* src; int base, R, C;
  if (idx < 278528) {
    if (idx < 131072) {
      if (idx < 65536) { base = 0;      src = s0; R = 256; C = 256; }
      else             { base = 65536;  src = s1; R = 256; C = 256; }
    } else {
      if (idx < 147456){ base = 131072; src = s2; R = 256; C = 64;  }
      else             { base = 147456; src = s3; R = 512; C = 256; }
    }
  } else {
    int j = idx - 278528;
    if (j < 131072) {
      if (j < 65536)   { base = 278528; src = s4; R = 256; C = 256; }
      else             { base = 344064; src = s5; R = 256; C = 256; }
    } else {
      if (j < 147456)  { base = 409600; src = s6; R = 256; C = 64;  }
      else             { base = 425984; src = s7; R = 512; C = 256; }
    }
  }
  int local = idx - base;
  int o = local / R;
  int k = local - o * R;
  dst[idx] = f2b(src[k * C + o]);   // dst[o][k] = src[k][o]
}

// ---------------------------------------------------------------------------
// Generic K=256 GEMM: C(N x NC) = [gelu](A @ B^T [+ bias]), all bf16 MFMA.
// Block = 128 threads (2 waves), 32 rows/wave, A staged per-wave in LDS
// (stride 264 -> 16B-aligned b128 reads, 2-way bank alias only).
// DUALOUT additionally writes C2 = gelu(C) (used for the concat-gelu input).
// ---------------------------------------------------------------------------
template<int NC, bool GELU, bool BIAS, bool AFP32, bool DUALOUT>
__global__ __launch_bounds__(128) void gemm_k256(
    const void* __restrict__ Av, const u16* __restrict__ BT,
    const float* __restrict__ bias, u16* __restrict__ Cout,
    u16* __restrict__ C2, int N)
{
  constexpr int K = 256;
  __shared__ u16 Asm[2][32][264];
  const int wave = threadIdx.x >> 6;
  const int lane = threadIdx.x & 63;
  const int r0 = blockIdx.x * 64 + wave * 32;

  if constexpr (AFP32) {
    const float* A = (const float*)Av;
    #pragma unroll 4
    for (int r = 0; r < 32; ++r) {
      float4 v = *(const float4*)(A + (size_t)(r0 + r) * K + lane * 4);
      uint2 p;
      p.x = (unsigned)f2b(v.x) | ((unsigned)f2b(v.y) << 16);
      p.y = (unsigned)f2b(v.z) | ((unsigned)f2b(v.w) << 16);
      *(uint2*)&Asm[wave][r][lane * 4] = p;
    }
  } else {
    const u16* A = (const u16*)Av;
    #pragma unroll 4
    for (int r = 0; r < 32; ++r) {
      uint2 p = *(const uint2*)(A + (size_t)(r0 + r) * K + lane * 4);
      *(uint2*)&Asm[wave][r][lane * 4] = p;
    }
  }
  __syncthreads();

  const int lm = lane & 15, lq = lane >> 4;
  #pragma unroll 1
  for (int n0 = 0; n0 < NC; n0 += 64) {
    f32x4 acc[2][4] = {};
    float bv[4];
    if constexpr (BIAS) {
      #pragma unroll
      for (int ct = 0; ct < 4; ++ct) bv[ct] = bias[n0 + ct * 16 + lm];
    }
    #pragma unroll
    for (int k0 = 0; k0 < K; k0 += 32) {
      bf16x8 a[2], b[4];
      #pragma unroll
      for (int rt = 0; rt < 2; ++rt)
        a[rt] = *(const bf16x8*)&Asm[wave][rt * 16 + lm][k0 + lq * 8];
      #pragma unroll
      for (int ct = 0; ct < 4; ++ct)
        b[ct] = *(const bf16x8*)(BT + (size_t)(n0 + ct * 16 + lm) * K + k0 + lq * 8);
      #pragma unroll
      for (int rt = 0; rt < 2; ++rt)
        #pragma unroll
        for (int ct = 0; ct < 4; ++ct)
          acc[rt][ct] = __builtin_amdgcn_mfma_f32_16x16x32_bf16(a[rt], b[ct], acc[rt][ct], 0, 0, 0);
    }
    #pragma unroll
    for (int rt = 0; rt < 2; ++rt)
      #pragma unroll
      for (int ct = 0; ct < 4; ++ct)
        #pragma unroll
        for (int rg = 0; rg < 4; ++rg) {
          float v = acc[rt][ct][rg];
          if constexpr (BIAS) v += bv[ct];
          if constexpr (GELU) v = gelu_f(v);
          size_t idx = (size_t)(r0 + rt * 16 + lq * 4 + rg) * NC + n0 + ct * 16 + lm;
          Cout[idx] = f2b(v);
          if constexpr (DUALOUT) C2[idx] = f2b(gelu_f(v));
        }
  }
}

// ---------------------------------------------------------------------------
// S partials: S[h][m] = sum_i Hf[i][h] * Wt[i][m]. Grid-stride over 64-node
// chunks; LDS-transpose staging so MFMA A/B frags are contiguous. Each of
// 512 blocks writes one 256x64 fp32 partial.
// ---------------------------------------------------------------------------
__global__ __launch_bounds__(256) void s_partial(
    const u16* __restrict__ Hf, const u16* __restrict__ Wt,
    float* __restrict__ Spart, int N)
{
  __shared__ u16 HfT[256][72];   // [h][i], stride 72 -> 144B rows (16B aligned)
  __shared__ u16 WtT[64][72];    // [m][i]
  const int tid = threadIdx.x;
  const int wave = tid >> 6, lane = tid & 63;
  const int lm = lane & 15, lq = lane >> 4;
  f32x4 acc[4][4] = {};
  const int nchunk = N / 64;
  for (int ch = blockIdx.x; ch < nchunk; ch += gridDim.x) {
    const int i0 = ch * 64;
    __syncthreads();
    {
      const int ii = tid >> 5;
      const int c8 = (tid & 31) * 8;
      #pragma unroll
      for (int p = 0; p < 8; ++p) {
        int row = ii + p * 8;
        uint4 v = *(const uint4*)(Hf + (size_t)(i0 + row) * 256 + c8);
        HfT[c8 + 0][row] = (u16)v.x; HfT[c8 + 1][row] = (u16)(v.x >> 16);
        HfT[c8 + 2][row] = (u16)v.y; HfT[c8 + 3][row] = (u16)(v.y >> 16);
        HfT[c8 + 4][row] = (u16)v.z; HfT[c8 + 5][row] = (u16)(v.z >> 16);
        HfT[c8 + 6][row] = (u16)v.w; HfT[c8 + 7][row] = (u16)(v.w >> 16);
      }
      const int iw = tid >> 3;
      const int cw = (tid & 7) * 8;
      #pragma unroll
      for (int p = 0; p < 2; ++p) {
        int row = iw + p * 32;
        uint4 v = *(const uint4*)(Wt + (size_t)(i0 + row) * 64 + cw);
        WtT[cw + 0][row] = (u16)v.x; WtT[cw + 1][row] = (u16)(v.x >> 16);
        WtT[cw + 2][row] = (u16)v.y; WtT[cw + 3][row] = (u16)(v.y >> 16);
        WtT[cw + 4][row] = (u16)v.z; WtT[cw + 5][row] = (u16)(v.z >> 16);
        WtT[cw + 6][row] = (u16)v.w; WtT[cw + 7][row] = (u16)(v.w >> 16);
      }
    }
    __syncthreads();
    #pragma unroll
    for (int k0 = 0; k0 < 64; k0 += 32) {
      bf16x8 a[4], b[4];
      #pragma unroll
      for (int t = 0; t < 4; ++t)
        a[t] = *(const bf16x8*)&HfT[wave * 64 + t * 16 + lm][k0 + lq * 8];
      #pragma unroll
      for (int m = 0; m < 4; ++m)
        b[m] = *(const bf16x8*)&WtT[m * 16 + lm][k0 + lq * 8];
      #pragma unroll
      for (int t = 0; t < 4; ++t)
        #pragma unroll
        for (int m = 0; m < 4; ++m)
          acc[t][m] = __builtin_amdgcn_mfma_f32_16x16x32_bf16(a[t], b[m], acc[t][m], 0, 0, 0);
    }
  }
  float* out = Spart + (size_t)blockIdx.x * 16384;
  #pragma unroll
  for (int t = 0; t < 4; ++t)
    #pragma unroll
    for (int m = 0; m < 4; ++m)
      #pragma unroll
      for (int rg = 0; rg < 4; ++rg)
        out[(size_t)(wave * 64 + t * 16 + lq * 4 + rg) * 64 + m * 16 + lm] = acc[t][m][rg];
}

__global__ __launch_bounds__(256) void s_reduce(
    const float* __restrict__ Spart, u16* __restrict__ agg, int nparts)
{
  int e = blockIdx.x * 256 + threadIdx.x;   // grid 64 -> 16384 elements
  float s = 0.0f;
  for (int p = 0; p < nparts; ++p) s += Spart[(size_t)p * 16384 + e];
  agg[e] = f2b(gelu_f(s));                  // agg[h][m], row-major 256x64
}

// ---------------------------------------------------------------------------
// Fused: P = gelu(Wt @ agg^T) (K=64) kept in LDS, then
// X = [P | gelu(Hf)] @ ff2^T + b  (K=512; second half A-frags from global Hfg).
// ---------------------------------------------------------------------------
__global__ __launch_bounds__(128) void fused_p_ff2(
    const u16* __restrict__ Wt, const u16* __restrict__ agg,
    const u16* __restrict__ Hfg, const u16* __restrict__ W2T,
    const float* __restrict__ bias, u16* __restrict__ X, int N)
{
  __shared__ u16 Pl[2][32][264];
  const int wave = threadIdx.x >> 6;
  const int lane = threadIdx.x & 63;
  const int r0 = blockIdx.x * 64 + wave * 32;
  const int lm = lane & 15, lq = lane >> 4;

  // stage 1: P tile -> LDS (gelu applied)
  #pragma unroll 1
  for (int n0 = 0; n0 < 256; n0 += 64) {
    f32x4 acc[2][4] = {};
    #pragma unroll
    for (int k0 = 0; k0 < 64; k0 += 32) {
      bf16x8 a[2], b[4];
      #pragma unroll
      for (int rt = 0; rt < 2; ++rt)
        a[rt] = *(const bf16x8*)(Wt + (size_t)(r0 + rt * 16 + lm) * 64 + k0 + lq * 8);
      #pragma unroll
      for (int ct = 0; ct < 4; ++ct)
        b[ct] = *(const bf16x8*)(agg + (size_t)(n0 + ct * 16 + lm) * 64 + k0 + lq * 8);
      #pragma unroll
      for (int rt = 0; rt < 2; ++rt)
        #pragma unroll
        for (int ct = 0; ct < 4; ++ct)
          acc[rt][ct] = __builtin_amdgcn_mfma_f32_16x16x32_bf16(a[rt], b[ct], acc[rt][ct], 0, 0, 0);
    }
    #pragma unroll
    for (int rt = 0; rt < 2; ++rt)
      #pragma unroll
      for (int ct = 0; ct < 4; ++ct)
        #pragma unroll
        for (int rg = 0; rg < 4; ++rg)
          Pl[wave][rt * 16 + lq * 4 + rg][n0 + ct * 16 + lm] = f2b(gelu_f(acc[rt][ct][rg]));
  }
  __syncthreads();

  // stage 2: X = [P | Hfg] @ W2T + b
  #pragma unroll 1
  for (int n0 = 0; n0 < 256; n0 += 64) {
    f32x4 acc[2][4] = {};
    float bv[4];
    #pragma unroll
    for (int ct = 0; ct < 4; ++ct) bv[ct] = bias[n0 + ct * 16 + lm];
    #pragma unroll
    for (int k0 = 0; k0 < 512; k0 += 32) {
      bf16x8 a[2], b[4];
      if (k0 < 256) {
        #pragma unroll
        for (int rt = 0; rt < 2; ++rt)
          a[rt] = *(const bf16x8*)&Pl[wave][rt * 16 + lm][k0 + lq * 8];
      } else {
        #pragma unroll
        for (int rt = 0; rt < 2; ++rt)
          a[rt] = *(const bf16x8*)(Hfg + (size_t)(r0 + rt * 16 + lm) * 256 + (k0 - 256) + lq * 8);
      }
      #pragma unroll
      for (int ct = 0; ct < 4; ++ct)
        b[ct] = *(const bf16x8*)(W2T + (size_t)(n0 + ct * 16 + lm) * 512 + k0 + lq * 8);
      #pragma unroll
      for (int rt = 0; rt < 2; ++rt)
        #pragma unroll
        for (int ct = 0; ct < 4; ++ct)
          acc[rt][ct] = __builtin_amdgcn_mfma_f32_16x16x32_bf16(a[rt], b[ct], acc[rt][ct], 0, 0, 0);
    }
    #pragma unroll
    for (int rt = 0; rt < 2; ++rt)
      #pragma unroll
      for (int ct = 0; ct < 4; ++ct)
        #pragma unroll
        for (int rg = 0; rg < 4; ++rg)
          X[(size_t)(r0 + rt * 16 + lq * 4 + rg) * 256 + n0 + ct * 16 + lm] =
              f2b(acc[rt][ct][rg] + bv[ct]);
  }
}

// ---------------------------------------------------------------------------
// Column sums of X2 (for the mean), then head.
// ---------------------------------------------------------------------------
__global__ __launch_bounds__(256) void colsum_kernel(
    const u16* __restrict__ X, float* __restrict__ colsum, int N)
{
  __shared__ float ls[256];
  const int tid = threadIdx.x;
  ls[tid] = 0.0f;
  __syncthreads();
  const int c8 = (tid & 31) * 8;
  const int rofs = tid >> 5;
  float a[8] = {};
  for (int r = blockIdx.x * 8 + rofs; r < N; r += gridDim.x * 8) {
    uint4 v = *(const uint4*)(X + (size_t)r * 256 + c8);
    a[0] += b2f((u16)v.x); a[1] += b2f((u16)(v.x >> 16));
    a[2] += b2f((u16)v.y); a[3] += b2f((u16)(v.y >> 16));
    a[4] += b2f((u16)v.z); a[5] += b2f((u16)(v.z >> 16));
    a[6] += b2f((u16)v.w); a[7] += b2f((u16)(v.w >> 16));
  }
  #pragma unroll
  for (int j = 0; j < 8; ++j) atomicAdd(&ls[c8 + j], a[j]);
  __syncthreads();
  atomicAdd(&colsum[tid], ls[tid]);
}

__global__ __launch_bounds__(64) void head_kernel(
    const float* __restrict__ colsum, const float* __restrict__ head_w,
    const float* __restrict__ head_b, float* __restrict__ out, float invN)
{
  const int c = threadIdx.x;   // 64
  float s = head_b[c];
  for (int h = 0; h < 256; ++h) s = fmaf(colsum[h] * invN, head_w[h * 64 + c], s);
  out[c] = s;
}

// ---------------------------------------------------------------------------
extern "C" void kernel_launch(void* const* d_in, const int* in_sizes, int n_in,
                              void* d_out, int out_size, void* d_ws, size_t ws_size,
                              hipStream_t stream)
{
  const float* x        = (const float*)d_in[0];
  // d_in[1] = edge_index: unused by the reference
  const float* ff1_w[2] = {(const float*)d_in[2],  (const float*)d_in[8]};
  const float* ff1_b[2] = {(const float*)d_in[3],  (const float*)d_in[9]};
  const float* wA[2]    = {(const float*)d_in[4],  (const float*)d_in[10]};
  const float* wB[2]    = {(const float*)d_in[5],  (const float*)d_in[11]};
  const float* ff2_w[2] = {(const float*)d_in[6],  (const float*)d_in[12]};
  const float* ff2_b[2] = {(const float*)d_in[7],  (const float*)d_in[13]};
  const float* head_w   = (const float*)d_in[14];
  const float* head_b   = (const float*)d_in[15];
  const int N = in_sizes[0] / 256;   // 200000, divisible by 64

  char* ws = (char*)d_ws;
  u16* WT = (u16*)ws;                       // 557056 bf16 elements
  u16* W1T[2] = {WT + 0,      WT + 278528};
  u16* wAT[2] = {WT + 65536,  WT + 344064};
  u16* wBT[2] = {WT + 131072, WT + 409600};
  u16* W2T[2] = {WT + 147456, WT + 425984};
  size_t o = 1114112;                       // 557056*2 bytes, 256-aligned
  u16* Hf  = (u16*)(ws + o); o += (size_t)N * 256 * 2;   // raw gelu(FF1)
  u16* Hfg = (u16*)(ws + o); o += (size_t)N * 256 * 2;   // gelu(Hf) for concat
  u16* TX  = (u16*)(ws + o); o += (size_t)N * 256 * 2;   // T / X1 / T2 / X2
  u16* Wt  = (u16*)(ws + o); o += (size_t)N * 64 * 2;    // W_tar
  float* Spart  = (float*)(ws + o); o += (size_t)512 * 16384 * 4;
  u16*   agg    = (u16*)(ws + o);   o += 16384 * 2;
  float* colsum = (float*)(ws + o); o += 256 * 4;
  (void)ws_size; (void)n_in; (void)out_size;

  hipMemsetAsync(colsum, 0, 256 * sizeof(float), stream);
  prep_weights<<<2176, 256, 0, stream>>>(ff1_w[0], wA[0], wB[0], ff2_w[0],
                                         ff1_w[1], wA[1], wB[1], ff2_w[1], WT);
  const int G = N / 64;   // 3125
  for (int blk = 0; blk < 2; ++blk) {
    if (blk == 0)
      gemm_k256<256, true, true, true,  true ><<<G, 128, 0, stream>>>(x,  W1T[0], ff1_b[0], Hf, Hfg, N);
    else
      gemm_k256<256, true, true, false, true ><<<G, 128, 0, stream>>>(TX, W1T[1], ff1_b[1], Hf, Hfg, N);
    gemm_k256<256, true,  false, false, false><<<G, 128, 0, stream>>>(Hf, wAT[blk], nullptr, TX, nullptr, N);
    gemm_k256<64,  false, false, false, false><<<G, 128, 0, stream>>>(TX, wBT[blk], nullptr, Wt, nullptr, N);
    s_partial<<<512, 256, 0, stream>>>(Hf, Wt, Spart, N);
    s_reduce<<<64, 256, 0, stream>>>(Spart, agg, 512);
    fused_p_ff2<<<G, 128, 0, stream>>>(Wt, agg, Hfg, W2T[blk], ff2_b[blk], TX, N);
  }
  colsum_kernel<<<256, 256, 0, stream>>>(TX, colsum, N);
  head_kernel<<<1, 64, 0, stream>>>(colsum, head_w, head_b, (float*)d_out, 1.0f / (float)N);
}

// Round 2
// 1666.146 us; speedup vs baseline: 1.2432x; 1.2432x over previous
//
#include <hip/hip_runtime.h>

// GHM_68143951118654 — bf16 MFMA, v2: 4-wave column-split GEMM blocks,
// fused wA+wB (hyper), colsum fused into final FF2 epilogue.

typedef unsigned short u16;
typedef short bf16x8 __attribute__((ext_vector_type(8)));
typedef float f32x4 __attribute__((ext_vector_type(4)));

__device__ __forceinline__ float gelu_f(float x) {
  return 0.5f * x * (1.0f + erff(x * 0.70710678118654752440f));
}
__device__ __forceinline__ u16 f2b(float f) {
  union { float f; unsigned u; } v; v.f = f;
  unsigned u = v.u;
  u += 0x7fffu + ((u >> 16) & 1u);   // round-to-nearest-even
  return (u16)(u >> 16);
}
__device__ __forceinline__ float b2f(u16 h) {
  union { unsigned u; float f; } v; v.u = ((unsigned)h) << 16;
  return v.f;
}

// ---------------------------------------------------------------------------
// Weight prep: fp32 -> bf16, transposed to [out][in].
// seg sizes (elements): 65536,65536,16384,131072  x2 blocks = 557056 total
// ---------------------------------------------------------------------------
__global__ __launch_bounds__(256) void prep_weights(
    const float* __restrict__ s0, const float* __restrict__ s1,
    const float* __restrict__ s2, const float* __restrict__ s3,
    const float* __restrict__ s4, const float* __restrict__ s5,
    const float* __restrict__ s6, const float* __restrict__ s7,
    u16* __restrict__ dst)
{
  int idx = blockIdx.x * 256 + threadIdx.x;
  if (idx >= 557056) return;
  const float* src; int base, R, C;
  if (idx < 278528) {
    if (idx < 131072) {
      if (idx < 65536) { base = 0;      src = s0; R = 256; C = 256; }
      else             { base = 65536;  src = s1; R = 256; C = 256; }
    } else {
      if (idx < 147456){ base = 131072; src = s2; R = 256; C = 64;  }
      else             { base = 147456; src = s3; R = 512; C = 256; }
    }
  } else {
    int j = idx - 278528;
    if (j < 131072) {
      if (j < 65536)   { base = 278528; src = s4; R = 256; C = 256; }
      else             { base = 344064; src = s5; R = 256; C = 256; }
    } else {
      if (j < 147456)  { base = 409600; src = s6; R = 256; C = 64;  }
      else             { base = 425984; src = s7; R = 512; C = 256; }
    }
  }
  int local = idx - base;
  int o = local / R;
  int k = local - o * R;
  dst[idx] = f2b(src[k * C + o]);   // dst[o][k] = src[k][o]
}

// ---------------------------------------------------------------------------
// FF1: Hf = gelu(A @ W^T + b), Hfg = gelu(Hf). 256 thr / 4 waves; block does
// 64 rows; wave w computes output cols [64w, 64w+64). A staged in LDS.
// ---------------------------------------------------------------------------
template<bool AFP32>
__global__ __launch_bounds__(256) void ff1_v2(
    const void* __restrict__ Av, const u16* __restrict__ BT,
    const float* __restrict__ bias, u16* __restrict__ Hf,
    u16* __restrict__ Hfg, int N)
{
  __shared__ u16 Asm[64][264];
  const int tid = threadIdx.x;
  const int wave = tid >> 6, lane = tid & 63;
  const int r0 = blockIdx.x * 64;
  {
    const int row = tid & 63;
    const int cseg = (tid >> 6) * 64;
    if constexpr (AFP32) {
      const float* A = (const float*)Av + (size_t)(r0 + row) * 256 + cseg;
      #pragma unroll
      for (int j = 0; j < 8; ++j) {
        float4 v0 = *(const float4*)(A + j * 8);
        float4 v1 = *(const float4*)(A + j * 8 + 4);
        uint4 p;
        p.x = (unsigned)f2b(v0.x) | ((unsigned)f2b(v0.y) << 16);
        p.y = (unsigned)f2b(v0.z) | ((unsigned)f2b(v0.w) << 16);
        p.z = (unsigned)f2b(v1.x) | ((unsigned)f2b(v1.y) << 16);
        p.w = (unsigned)f2b(v1.z) | ((unsigned)f2b(v1.w) << 16);
        *(uint4*)&Asm[row][cseg + j * 8] = p;
      }
    } else {
      const u16* A = (const u16*)Av + (size_t)(r0 + row) * 256 + cseg;
      #pragma unroll
      for (int j = 0; j < 8; ++j)
        *(uint4*)&Asm[row][cseg + j * 8] = *(const uint4*)(A + j * 8);
    }
  }
  __syncthreads();

  const int lm = lane & 15, lq = lane >> 4;
  const int n0 = wave * 64;
  f32x4 acc[4][4] = {};
  #pragma unroll
  for (int k0 = 0; k0 < 256; k0 += 32) {
    bf16x8 a[4], b[4];
    #pragma unroll
    for (int rt = 0; rt < 4; ++rt)
      a[rt] = *(const bf16x8*)&Asm[rt * 16 + lm][k0 + lq * 8];
    #pragma unroll
    for (int ct = 0; ct < 4; ++ct)
      b[ct] = *(const bf16x8*)(BT + (size_t)(n0 + ct * 16 + lm) * 256 + k0 + lq * 8);
    #pragma unroll
    for (int rt = 0; rt < 4; ++rt)
      #pragma unroll
      for (int ct = 0; ct < 4; ++ct)
        acc[rt][ct] = __builtin_amdgcn_mfma_f32_16x16x32_bf16(a[rt], b[ct], acc[rt][ct], 0, 0, 0);
  }
  float bv[4];
  #pragma unroll
  for (int ct = 0; ct < 4; ++ct) bv[ct] = bias[n0 + ct * 16 + lm];
  #pragma unroll
  for (int rt = 0; rt < 4; ++rt)
    #pragma unroll
    for (int ct = 0; ct < 4; ++ct)
      #pragma unroll
      for (int rg = 0; rg < 4; ++rg) {
        float g = gelu_f(acc[rt][ct][rg] + bv[ct]);
        size_t idx = (size_t)(r0 + rt * 16 + lq * 4 + rg) * 256 + n0 + ct * 16 + lm;
        Hf[idx] = f2b(g);
        Hfg[idx] = f2b(gelu_f(g));
      }
}

// ---------------------------------------------------------------------------
// hyper: Wt = gelu(Hf @ wA) @ wB, fused. T tile lives in LDS (overwrites the
// staged Hf tile after a sync). 256 thr / 4 waves, 64 rows per block.
// ---------------------------------------------------------------------------
__global__ __launch_bounds__(256) void hyper_v2(
    const u16* __restrict__ Hf, const u16* __restrict__ wAT,
    const u16* __restrict__ wBT, u16* __restrict__ Wt, int N)
{
  __shared__ u16 Asm[64][264];
  const int tid = threadIdx.x;
  const int wave = tid >> 6, lane = tid & 63;
  const int r0 = blockIdx.x * 64;
  {
    const int row = tid & 63;
    const int cseg = (tid >> 6) * 64;
    const u16* A = Hf + (size_t)(r0 + row) * 256 + cseg;
    #pragma unroll
    for (int j = 0; j < 8; ++j)
      *(uint4*)&Asm[row][cseg + j * 8] = *(const uint4*)(A + j * 8);
  }
  __syncthreads();

  const int lm = lane & 15, lq = lane >> 4;
  const int n0 = wave * 64;
  // T = gelu(Hf @ wA^T), cols [n0, n0+64) per wave
  f32x4 acc[4][4] = {};
  #pragma unroll
  for (int k0 = 0; k0 < 256; k0 += 32) {
    bf16x8 a[4], b[4];
    #pragma unroll
    for (int rt = 0; rt < 4; ++rt)
      a[rt] = *(const bf16x8*)&Asm[rt * 16 + lm][k0 + lq * 8];
    #pragma unroll
    for (int ct = 0; ct < 4; ++ct)
      b[ct] = *(const bf16x8*)(wAT + (size_t)(n0 + ct * 16 + lm) * 256 + k0 + lq * 8);
    #pragma unroll
    for (int rt = 0; rt < 4; ++rt)
      #pragma unroll
      for (int ct = 0; ct < 4; ++ct)
        acc[rt][ct] = __builtin_amdgcn_mfma_f32_16x16x32_bf16(a[rt], b[ct], acc[rt][ct], 0, 0, 0);
  }
  __syncthreads();   // everyone done reading Hf tile
  #pragma unroll
  for (int rt = 0; rt < 4; ++rt)
    #pragma unroll
    for (int ct = 0; ct < 4; ++ct)
      #pragma unroll
      for (int rg = 0; rg < 4; ++rg)
        Asm[rt * 16 + lq * 4 + rg][n0 + ct * 16 + lm] = f2b(gelu_f(acc[rt][ct][rg]));
  __syncthreads();

  // Wt = T @ wB^T: wave w handles rows [16w, 16w+16), all 64 cols
  f32x4 acc2[4] = {};
  #pragma unroll
  for (int k0 = 0; k0 < 256; k0 += 32) {
    bf16x8 a = *(const bf16x8*)&Asm[wave * 16 + lm][k0 + lq * 8];
    #pragma unroll
    for (int ct = 0; ct < 4; ++ct) {
      bf16x8 b = *(const bf16x8*)(wBT + (size_t)(ct * 16 + lm) * 256 + k0 + lq * 8);
      acc2[ct] = __builtin_amdgcn_mfma_f32_16x16x32_bf16(a, b, acc2[ct], 0, 0, 0);
    }
  }
  #pragma unroll
  for (int ct = 0; ct < 4; ++ct)
    #pragma unroll
    for (int rg = 0; rg < 4; ++rg)
      Wt[(size_t)(r0 + wave * 16 + lq * 4 + rg) * 64 + ct * 16 + lm] = f2b(acc2[ct][rg]);
}

// ---------------------------------------------------------------------------
// S partials: S[h][m] = sum_i Hf[i][h]*Wt[i][m]; 512 partial tiles + reduce.
// ---------------------------------------------------------------------------
__global__ __launch_bounds__(256) void s_partial(
    const u16* __restrict__ Hf, const u16* __restrict__ Wt,
    float* __restrict__ Spart, int N)
{
  __shared__ u16 HfT[256][72];
  __shared__ u16 WtT[64][72];
  const int tid = threadIdx.x;
  const int wave = tid >> 6, lane = tid & 63;
  const int lm = lane & 15, lq = lane >> 4;
  f32x4 acc[4][4] = {};
  const int nchunk = N / 64;
  for (int ch = blockIdx.x; ch < nchunk; ch += gridDim.x) {
    const int i0 = ch * 64;
    __syncthreads();
    {
      const int ii = tid >> 5;
      const int c8 = (tid & 31) * 8;
      #pragma unroll
      for (int p = 0; p < 8; ++p) {
        int row = ii + p * 8;
        uint4 v = *(const uint4*)(Hf + (size_t)(i0 + row) * 256 + c8);
        HfT[c8 + 0][row] = (u16)v.x; HfT[c8 + 1][row] = (u16)(v.x >> 16);
        HfT[c8 + 2][row] = (u16)v.y; HfT[c8 + 3][row] = (u16)(v.y >> 16);
        HfT[c8 + 4][row] = (u16)v.z; HfT[c8 + 5][row] = (u16)(v.z >> 16);
        HfT[c8 + 6][row] = (u16)v.w; HfT[c8 + 7][row] = (u16)(v.w >> 16);
      }
      const int iw = tid >> 3;
      const int cw = (tid & 7) * 8;
      #pragma unroll
      for (int p = 0; p < 2; ++p) {
        int row = iw + p * 32;
        uint4 v = *(const uint4*)(Wt + (size_t)(i0 + row) * 64 + cw);
        WtT[cw + 0][row] = (u16)v.x; WtT[cw + 1][row] = (u16)(v.x >> 16);
        WtT[cw + 2][row] = (u16)v.y; WtT[cw + 3][row] = (u16)(v.y >> 16);
        WtT[cw + 4][row] = (u16)v.z; WtT[cw + 5][row] = (u16)(v.z >> 16);
        WtT[cw + 6][row] = (u16)v.w; WtT[cw + 7][row] = (u16)(v.w >> 16);
      }
    }
    __syncthreads();
    #pragma unroll
    for (int k0 = 0; k0 < 64; k0 += 32) {
      bf16x8 a[4], b[4];
      #pragma unroll
      for (int t = 0; t < 4; ++t)
        a[t] = *(const bf16x8*)&HfT[wave * 64 + t * 16 + lm][k0 + lq * 8];
      #pragma unroll
      for (int m = 0; m < 4; ++m)
        b[m] = *(const bf16x8*)&WtT[m * 16 + lm][k0 + lq * 8];
      #pragma unroll
      for (int t = 0; t < 4; ++t)
        #pragma unroll
        for (int m = 0; m < 4; ++m)
          acc[t][m] = __builtin_amdgcn_mfma_f32_16x16x32_bf16(a[t], b[m], acc[t][m], 0, 0, 0);
    }
  }
  float* out = Spart + (size_t)blockIdx.x * 16384;
  #pragma unroll
  for (int t = 0; t < 4; ++t)
    #pragma unroll
    for (int m = 0; m < 4; ++m)
      #pragma unroll
      for (int rg = 0; rg < 4; ++rg)
        out[(size_t)(wave * 64 + t * 16 + lq * 4 + rg) * 64 + m * 16 + lm] = acc[t][m][rg];
}

__global__ __launch_bounds__(256) void s_reduce(
    const float* __restrict__ Spart, u16* __restrict__ agg, int nparts)
{
  int e = blockIdx.x * 256 + threadIdx.x;   // grid 64 -> 16384 elements
  float s = 0.0f;
  for (int p = 0; p < nparts; ++p) s += Spart[(size_t)p * 16384 + e];
  agg[e] = f2b(gelu_f(s));                  // agg[h][m], row-major 256x64
}

// ---------------------------------------------------------------------------
// Fused: P = gelu(Wt @ agg^T) into LDS, then X = [P | gelu(Hf)] @ ff2^T + b.
// 4 waves split the 256 output cols. COLSUM: skip X store, accumulate the
// global column sums via shuffle-reduce + one atomic per col per block.
// ---------------------------------------------------------------------------
template<bool COLSUM>
__global__ __launch_bounds__(256) void fused_p_ff2_v3(
    const u16* __restrict__ Wt, const u16* __restrict__ agg,
    const u16* __restrict__ Hfg, const u16* __restrict__ W2T,
    const float* __restrict__ bias, u16* __restrict__ X,
    float* __restrict__ colsum, int N)
{
  __shared__ u16 Pl[64][264];
  const int tid = threadIdx.x;
  const int wave = tid >> 6, lane = tid & 63;
  const int lm = lane & 15, lq = lane >> 4;
  const int r0 = blockIdx.x * 64;
  const int n0 = wave * 64;

  // stage 1: P cols [n0, n0+64) -> LDS (gelu applied)
  {
    f32x4 acc[4][4] = {};
    #pragma unroll
    for (int k0 = 0; k0 < 64; k0 += 32) {
      bf16x8 a[4], b[4];
      #pragma unroll
      for (int rt = 0; rt < 4; ++rt)
        a[rt] = *(const bf16x8*)(Wt + (size_t)(r0 + rt * 16 + lm) * 64 + k0 + lq * 8);
      #pragma unroll
      for (int ct = 0; ct < 4; ++ct)
        b[ct] = *(const bf16x8*)(agg + (size_t)(n0 + ct * 16 + lm) * 64 + k0 + lq * 8);
      #pragma unroll
      for (int rt = 0; rt < 4; ++rt)
        #pragma unroll
        for (int ct = 0; ct < 4; ++ct)
          acc[rt][ct] = __builtin_amdgcn_mfma_f32_16x16x32_bf16(a[rt], b[ct], acc[rt][ct], 0, 0, 0);
    }
    #pragma unroll
    for (int rt = 0; rt < 4; ++rt)
      #pragma unroll
      for (int ct = 0; ct < 4; ++ct)
        #pragma unroll
        for (int rg = 0; rg < 4; ++rg)
          Pl[rt * 16 + lq * 4 + rg][n0 + ct * 16 + lm] = f2b(gelu_f(acc[rt][ct][rg]));
  }
  __syncthreads();

  // stage 2: X = [P | Hfg] @ W2T + b, cols [n0, n0+64) per wave
  f32x4 acc[4][4] = {};
  #pragma unroll
  for (int k0 = 0; k0 < 512; k0 += 32) {
    bf16x8 a[4], b[4];
    if (k0 < 256) {
      #pragma unroll
      for (int rt = 0; rt < 4; ++rt)
        a[rt] = *(const bf16x8*)&Pl[rt * 16 + lm][k0 + lq * 8];
    } else {
      #pragma unroll
      for (int rt = 0; rt < 4; ++rt)
        a[rt] = *(const bf16x8*)(Hfg + (size_t)(r0 + rt * 16 + lm) * 256 + (k0 - 256) + lq * 8);
    }
    #pragma unroll
    for (int ct = 0; ct < 4; ++ct)
      b[ct] = *(const bf16x8*)(W2T + (size_t)(n0 + ct * 16 + lm) * 512 + k0 + lq * 8);
    #pragma unroll
    for (int rt = 0; rt < 4; ++rt)
      #pragma unroll
      for (int ct = 0; ct < 4; ++ct)
        acc[rt][ct] = __builtin_amdgcn_mfma_f32_16x16x32_bf16(a[rt], b[ct], acc[rt][ct], 0, 0, 0);
  }
  float bv[4];
  #pragma unroll
  for (int ct = 0; ct < 4; ++ct) bv[ct] = bias[n0 + ct * 16 + lm];
  if constexpr (!COLSUM) {
    #pragma unroll
    for (int rt = 0; rt < 4; ++rt)
      #pragma unroll
      for (int ct = 0; ct < 4; ++ct)
        #pragma unroll
        for (int rg = 0; rg < 4; ++rg)
          X[(size_t)(r0 + rt * 16 + lq * 4 + rg) * 256 + n0 + ct * 16 + lm] =
              f2b(acc[rt][ct][rg] + bv[ct]);
  } else {
    #pragma unroll
    for (int ct = 0; ct < 4; ++ct) {
      float cs = 16.0f * bv[ct];
      #pragma unroll
      for (int rt = 0; rt < 4; ++rt)
        #pragma unroll
        for (int rg = 0; rg < 4; ++rg) cs += acc[rt][ct][rg];
      cs += __shfl_down(cs, 32);
      cs += __shfl_down(cs, 16);
      if (lq == 0) atomicAdd(&colsum[n0 + ct * 16 + lm], cs);
    }
  }
}

__global__ __launch_bounds__(64) void head_kernel(
    const float* __restrict__ colsum, const float* __restrict__ head_w,
    const float* __restrict__ head_b, float* __restrict__ out, float invN)
{
  const int c = threadIdx.x;   // 64
  float s = head_b[c];
  for (int h = 0; h < 256; ++h) s = fmaf(colsum[h] * invN, head_w[h * 64 + c], s);
  out[c] = s;
}

// ---------------------------------------------------------------------------
extern "C" void kernel_launch(void* const* d_in, const int* in_sizes, int n_in,
                              void* d_out, int out_size, void* d_ws, size_t ws_size,
                              hipStream_t stream)
{
  const float* x        = (const float*)d_in[0];
  // d_in[1] = edge_index: unused by the reference
  const float* ff1_w[2] = {(const float*)d_in[2],  (const float*)d_in[8]};
  const float* ff1_b[2] = {(const float*)d_in[3],  (const float*)d_in[9]};
  const float* wA[2]    = {(const float*)d_in[4],  (const float*)d_in[10]};
  const float* wB[2]    = {(const float*)d_in[5],  (const float*)d_in[11]};
  const float* ff2_w[2] = {(const float*)d_in[6],  (const float*)d_in[12]};
  const float* ff2_b[2] = {(const float*)d_in[7],  (const float*)d_in[13]};
  const float* head_w   = (const float*)d_in[14];
  const float* head_b   = (const float*)d_in[15];
  const int N = in_sizes[0] / 256;   // 200000, divisible by 64

  char* ws = (char*)d_ws;
  u16* WT = (u16*)ws;                       // 557056 bf16 elements
  u16* W1T[2] = {WT + 0,      WT + 278528};
  u16* wAT[2] = {WT + 65536,  WT + 344064};
  u16* wBT[2] = {WT + 131072, WT + 409600};
  u16* W2T[2] = {WT + 147456, WT + 425984};
  size_t o = 1114112;                       // 557056*2 bytes, 256-aligned
  u16* Hf  = (u16*)(ws + o); o += (size_t)N * 256 * 2;   // gelu(FF1)
  u16* Hfg = (u16*)(ws + o); o += (size_t)N * 256 * 2;   // gelu(Hf) for concat
  u16* TX  = (u16*)(ws + o); o += (size_t)N * 256 * 2;   // X1 (block-0 output)
  u16* Wt  = (u16*)(ws + o); o += (size_t)N * 64 * 2;    // W_tar
  float* Spart  = (float*)(ws + o); o += (size_t)512 * 16384 * 4;
  u16*   agg    = (u16*)(ws + o);   o += 16384 * 2;
  float* colsum = (float*)(ws + o); o += 256 * 4;
  (void)ws_size; (void)n_in; (void)out_size;

  hipMemsetAsync(colsum, 0, 256 * sizeof(float), stream);
  prep_weights<<<2176, 256, 0, stream>>>(ff1_w[0], wA[0], wB[0], ff2_w[0],
                                         ff1_w[1], wA[1], wB[1], ff2_w[1], WT);
  const int G = N / 64;   // 3125
  // block 0
  ff1_v2<true><<<G, 256, 0, stream>>>(x, W1T[0], ff1_b[0], Hf, Hfg, N);
  hyper_v2<<<G, 256, 0, stream>>>(Hf, wAT[0], wBT[0], Wt, N);
  s_partial<<<512, 256, 0, stream>>>(Hf, Wt, Spart, N);
  s_reduce<<<64, 256, 0, stream>>>(Spart, agg, 512);
  fused_p_ff2_v3<false><<<G, 256, 0, stream>>>(Wt, agg, Hfg, W2T[0], ff2_b[0], TX, nullptr, N);
  // block 1
  ff1_v2<false><<<G, 256, 0, stream>>>(TX, W1T[1], ff1_b[1], Hf, Hfg, N);
  hyper_v2<<<G, 256, 0, stream>>>(Hf, wAT[1], wBT[1], Wt, N);
  s_partial<<<512, 256, 0, stream>>>(Hf, Wt, Spart, N);
  s_reduce<<<64, 256, 0, stream>>>(Spart, agg, 512);
  fused_p_ff2_v3<true><<<G, 256, 0, stream>>>(Wt, agg, Hfg, W2T[1], ff2_b[1], nullptr, colsum, N);
  head_kernel<<<1, 64, 0, stream>>>(colsum, head_w, head_b, (float*)d_out, 1.0f / (float)N);
}

// Round 3
// 1470.098 us; speedup vs baseline: 1.4090x; 1.1334x over previous
//
#include <hip/hip_runtime.h>

// GHM_68143951118654 — bf16 MFMA, v3: 128-row GEMM blocks (acc[8][4]),
// conflict-free pair-packed transpose in s_partial, colsum fused in FF2.

typedef unsigned short u16;
typedef unsigned int u32;
typedef short bf16x8 __attribute__((ext_vector_type(8)));
typedef float f32x4 __attribute__((ext_vector_type(4)));

__device__ __forceinline__ float gelu_f(float x) {
  return 0.5f * x * (1.0f + erff(x * 0.70710678118654752440f));
}
__device__ __forceinline__ u16 f2b(float f) {
  union { float f; unsigned u; } v; v.f = f;
  unsigned u = v.u;
  u += 0x7fffu + ((u >> 16) & 1u);   // round-to-nearest-even
  return (u16)(u >> 16);
}
__device__ __forceinline__ float b2f(u16 h) {
  union { unsigned u; float f; } v; v.u = ((unsigned)h) << 16;
  return v.f;
}

// ---------------------------------------------------------------------------
// Weight prep: fp32 -> bf16, transposed to [out][in].
// ---------------------------------------------------------------------------
__global__ __launch_bounds__(256) void prep_weights(
    const float* __restrict__ s0, const float* __restrict__ s1,
    const float* __restrict__ s2, const float* __restrict__ s3,
    const float* __restrict__ s4, const float* __restrict__ s5,
    const float* __restrict__ s6, const float* __restrict__ s7,
    u16* __restrict__ dst)
{
  int idx = blockIdx.x * 256 + threadIdx.x;
  if (idx >= 557056) return;
  const float* src; int base, R, C;
  if (idx < 278528) {
    if (idx < 131072) {
      if (idx < 65536) { base = 0;      src = s0; R = 256; C = 256; }
      else             { base = 65536;  src = s1; R = 256; C = 256; }
    } else {
      if (idx < 147456){ base = 131072; src = s2; R = 256; C = 64;  }
      else             { base = 147456; src = s3; R = 512; C = 256; }
    }
  } else {
    int j = idx - 278528;
    if (j < 131072) {
      if (j < 65536)   { base = 278528; src = s4; R = 256; C = 256; }
      else             { base = 344064; src = s5; R = 256; C = 256; }
    } else {
      if (j < 147456)  { base = 409600; src = s6; R = 256; C = 64;  }
      else             { base = 425984; src = s7; R = 512; C = 256; }
    }
  }
  int local = idx - base;
  int o = local / R;
  int k = local - o * R;
  dst[idx] = f2b(src[k * C + o]);   // dst[o][k] = src[k][o]
}

// ---------------------------------------------------------------------------
// FF1: Hf = gelu(A @ W^T + b), Hfg = gelu(Hf). 128 rows/block, 4 waves
// col-split (64 cols each), acc[8][4].
// ---------------------------------------------------------------------------
template<bool AFP32>
__global__ __launch_bounds__(256, 2) void ff1_v3(
    const void* __restrict__ Av, const u16* __restrict__ BT,
    const float* __restrict__ bias, u16* __restrict__ Hf,
    u16* __restrict__ Hfg, int N)
{
  __shared__ u16 Asm[128][264];
  const int tid = threadIdx.x;
  const int wave = tid >> 6, lane = tid & 63;
  int r0 = blockIdx.x * 128;
  if (r0 > N - 128) r0 = N - 128;

  if constexpr (AFP32) {
    const float* A = (const float*)Av;
    #pragma unroll
    for (int j = 0; j < 32; ++j) {
      int idx = j * 256 + tid;
      int row = idx >> 6, c4 = idx & 63;
      float4 v = *(const float4*)(A + (size_t)(r0 + row) * 256 + c4 * 4);
      uint2 p;
      p.x = (u32)f2b(v.x) | ((u32)f2b(v.y) << 16);
      p.y = (u32)f2b(v.z) | ((u32)f2b(v.w) << 16);
      *(uint2*)&Asm[row][c4 * 4] = p;
    }
  } else {
    const u16* A = (const u16*)Av;
    #pragma unroll
    for (int j = 0; j < 16; ++j) {
      int idx = j * 256 + tid;
      int row = idx >> 5, c8 = idx & 31;
      *(uint4*)&Asm[row][c8 * 8] =
          *(const uint4*)(A + (size_t)(r0 + row) * 256 + c8 * 8);
    }
  }
  __syncthreads();

  const int lm = lane & 15, lq = lane >> 4;
  const int n0 = wave * 64;
  f32x4 acc[8][4] = {};
  #pragma unroll 2
  for (int k0 = 0; k0 < 256; k0 += 32) {
    bf16x8 a[8], b[4];
    #pragma unroll
    for (int ct = 0; ct < 4; ++ct)
      b[ct] = *(const bf16x8*)(BT + (size_t)(n0 + ct * 16 + lm) * 256 + k0 + lq * 8);
    #pragma unroll
    for (int rt = 0; rt < 8; ++rt)
      a[rt] = *(const bf16x8*)&Asm[rt * 16 + lm][k0 + lq * 8];
    #pragma unroll
    for (int rt = 0; rt < 8; ++rt)
      #pragma unroll
      for (int ct = 0; ct < 4; ++ct)
        acc[rt][ct] = __builtin_amdgcn_mfma_f32_16x16x32_bf16(a[rt], b[ct], acc[rt][ct], 0, 0, 0);
  }
  float bv[4];
  #pragma unroll
  for (int ct = 0; ct < 4; ++ct) bv[ct] = bias[n0 + ct * 16 + lm];
  #pragma unroll
  for (int rt = 0; rt < 8; ++rt)
    #pragma unroll
    for (int ct = 0; ct < 4; ++ct)
      #pragma unroll
      for (int rg = 0; rg < 4; ++rg) {
        float g = gelu_f(acc[rt][ct][rg] + bv[ct]);
        size_t idx = (size_t)(r0 + rt * 16 + lq * 4 + rg) * 256 + n0 + ct * 16 + lm;
        Hf[idx] = f2b(g);
        Hfg[idx] = f2b(gelu_f(g));
      }
}

// ---------------------------------------------------------------------------
// hyper: Wt = gelu(Hf @ wA^T) @ wB^T. 128 rows/block; T tile overwrites the
// staged Hf tile in LDS; stage2 row-split (32 rows/wave).
// ---------------------------------------------------------------------------
__global__ __launch_bounds__(256, 2) void hyper_v3(
    const u16* __restrict__ Hf, const u16* __restrict__ wAT,
    const u16* __restrict__ wBT, u16* __restrict__ Wt, int N)
{
  __shared__ u16 Asm[128][264];
  const int tid = threadIdx.x;
  const int wave = tid >> 6, lane = tid & 63;
  int r0 = blockIdx.x * 128;
  if (r0 > N - 128) r0 = N - 128;
  {
    #pragma unroll
    for (int j = 0; j < 16; ++j) {
      int idx = j * 256 + tid;
      int row = idx >> 5, c8 = idx & 31;
      *(uint4*)&Asm[row][c8 * 8] =
          *(const uint4*)(Hf + (size_t)(r0 + row) * 256 + c8 * 8);
    }
  }
  __syncthreads();

  const int lm = lane & 15, lq = lane >> 4;
  const int n0 = wave * 64;
  f32x4 acc[8][4] = {};
  #pragma unroll 2
  for (int k0 = 0; k0 < 256; k0 += 32) {
    bf16x8 a[8], b[4];
    #pragma unroll
    for (int ct = 0; ct < 4; ++ct)
      b[ct] = *(const bf16x8*)(wAT + (size_t)(n0 + ct * 16 + lm) * 256 + k0 + lq * 8);
    #pragma unroll
    for (int rt = 0; rt < 8; ++rt)
      a[rt] = *(const bf16x8*)&Asm[rt * 16 + lm][k0 + lq * 8];
    #pragma unroll
    for (int rt = 0; rt < 8; ++rt)
      #pragma unroll
      for (int ct = 0; ct < 4; ++ct)
        acc[rt][ct] = __builtin_amdgcn_mfma_f32_16x16x32_bf16(a[rt], b[ct], acc[rt][ct], 0, 0, 0);
  }
  __syncthreads();   // all waves done reading Hf tile
  #pragma unroll
  for (int rt = 0; rt < 8; ++rt)
    #pragma unroll
    for (int ct = 0; ct < 4; ++ct)
      #pragma unroll
      for (int rg = 0; rg < 4; ++rg)
        Asm[rt * 16 + lq * 4 + rg][n0 + ct * 16 + lm] = f2b(gelu_f(acc[rt][ct][rg]));
  __syncthreads();

  // stage2: Wt rows [32*wave, 32*wave+32), all 64 cols
  f32x4 acc2[2][4] = {};
  #pragma unroll 2
  for (int k0 = 0; k0 < 256; k0 += 32) {
    bf16x8 a[2], b[4];
    #pragma unroll
    for (int ct = 0; ct < 4; ++ct)
      b[ct] = *(const bf16x8*)(wBT + (size_t)(ct * 16 + lm) * 256 + k0 + lq * 8);
    #pragma unroll
    for (int rt = 0; rt < 2; ++rt)
      a[rt] = *(const bf16x8*)&Asm[wave * 32 + rt * 16 + lm][k0 + lq * 8];
    #pragma unroll
    for (int rt = 0; rt < 2; ++rt)
      #pragma unroll
      for (int ct = 0; ct < 4; ++ct)
        acc2[rt][ct] = __builtin_amdgcn_mfma_f32_16x16x32_bf16(a[rt], b[ct], acc2[rt][ct], 0, 0, 0);
  }
  #pragma unroll
  for (int rt = 0; rt < 2; ++rt)
    #pragma unroll
    for (int ct = 0; ct < 4; ++ct)
      #pragma unroll
      for (int rg = 0; rg < 4; ++rg)
        Wt[(size_t)(r0 + wave * 32 + rt * 16 + lq * 4 + rg) * 64 + ct * 16 + lm] =
            f2b(acc2[rt][ct][rg]);
}

// ---------------------------------------------------------------------------
// S partials: S[h][m] = sum_i Hf[i][h]*Wt[i][m]. Pair-packed b32 transpose,
// bank-conflict-free (bank = (4j + rp) % 32, 2-way).
// ---------------------------------------------------------------------------
__global__ __launch_bounds__(256) void s_partial(
    const u16* __restrict__ Hf, const u16* __restrict__ Wt,
    float* __restrict__ Spart, int N)
{
  __shared__ u16 HfT[256][72];   // [h][i], stride 144B (16B-aligned rows)
  __shared__ u16 WtT[64][72];    // [m][i]
  const int tid = threadIdx.x;
  const int wave = tid >> 6, lane = tid & 63;
  const int lm = lane & 15, lq = lane >> 4;
  const int rp = tid & 31;        // row-pair: i = 2rp, 2rp+1
  const int mb = tid >> 5;        // 0..7
  f32x4 acc[4][4] = {};
  const int nchunk = N >> 6;      // exact: N % 64 == 0
  for (int ch = blockIdx.x; ch < nchunk; ch += gridDim.x) {
    const int i0 = ch << 6;
    __syncthreads();
    #pragma unroll
    for (int q = 0; q < 4; ++q) {
      int m = mb + 8 * q;
      const u16* px = Hf + (size_t)(i0 + 2 * rp) * 256 + m * 8;
      uint4 xv = *(const uint4*)px;
      uint4 yv = *(const uint4*)(px + 256);
      u32 xs[4] = {xv.x, xv.y, xv.z, xv.w};
      u32 ys[4] = {yv.x, yv.y, yv.z, yv.w};
      #pragma unroll
      for (int t = 0; t < 4; ++t) {
        *(u32*)&HfT[m * 8 + 2 * t][2 * rp]     = (xs[t] & 0xFFFFu) | (ys[t] << 16);
        *(u32*)&HfT[m * 8 + 2 * t + 1][2 * rp] = (xs[t] >> 16) | (ys[t] & 0xFFFF0000u);
      }
    }
    {
      const u16* px = Wt + (size_t)(i0 + 2 * rp) * 64 + mb * 8;
      uint4 xv = *(const uint4*)px;
      uint4 yv = *(const uint4*)(px + 64);
      u32 xs[4] = {xv.x, xv.y, xv.z, xv.w};
      u32 ys[4] = {yv.x, yv.y, yv.z, yv.w};
      #pragma unroll
      for (int t = 0; t < 4; ++t) {
        *(u32*)&WtT[mb * 8 + 2 * t][2 * rp]     = (xs[t] & 0xFFFFu) | (ys[t] << 16);
        *(u32*)&WtT[mb * 8 + 2 * t + 1][2 * rp] = (xs[t] >> 16) | (ys[t] & 0xFFFF0000u);
      }
    }
    __syncthreads();
    #pragma unroll
    for (int k0 = 0; k0 < 64; k0 += 32) {
      bf16x8 a[4], b[4];
      #pragma unroll
      for (int t = 0; t < 4; ++t)
        a[t] = *(const bf16x8*)&HfT[wave * 64 + t * 16 + lm][k0 + lq * 8];
      #pragma unroll
      for (int m = 0; m < 4; ++m)
        b[m] = *(const bf16x8*)&WtT[m * 16 + lm][k0 + lq * 8];
      #pragma unroll
      for (int t = 0; t < 4; ++t)
        #pragma unroll
        for (int m = 0; m < 4; ++m)
          acc[t][m] = __builtin_amdgcn_mfma_f32_16x16x32_bf16(a[t], b[m], acc[t][m], 0, 0, 0);
    }
  }
  float* out = Spart + (size_t)blockIdx.x * 16384;
  #pragma unroll
  for (int t = 0; t < 4; ++t)
    #pragma unroll
    for (int m = 0; m < 4; ++m)
      #pragma unroll
      for (int rg = 0; rg < 4; ++rg)
        out[(size_t)(wave * 64 + t * 16 + lq * 4 + rg) * 64 + m * 16 + lm] = acc[t][m][rg];
}

__global__ __launch_bounds__(256) void s_reduce(
    const float* __restrict__ Spart, u16* __restrict__ agg, int nparts)
{
  int e = blockIdx.x * 256 + threadIdx.x;   // grid 64 -> 16384 elements
  float s0 = 0.f, s1 = 0.f, s2 = 0.f, s3 = 0.f;
  for (int p = 0; p < nparts; p += 4) {
    s0 += Spart[(size_t)(p + 0) * 16384 + e];
    s1 += Spart[(size_t)(p + 1) * 16384 + e];
    s2 += Spart[(size_t)(p + 2) * 16384 + e];
    s3 += Spart[(size_t)(p + 3) * 16384 + e];
  }
  agg[e] = f2b(gelu_f((s0 + s1) + (s2 + s3)));
}

// ---------------------------------------------------------------------------
// Fused: P = gelu(Wt @ agg^T) into LDS (128x256), then
// X = [P | gelu(Hf)] @ ff2^T + b. COLSUM: masked column-sum instead of store.
// ---------------------------------------------------------------------------
template<bool COLSUM>
__global__ __launch_bounds__(256, 2) void fused_p_ff2_v4(
    const u16* __restrict__ Wt, const u16* __restrict__ agg,
    const u16* __restrict__ Hfg, const u16* __restrict__ W2T,
    const float* __restrict__ bias, u16* __restrict__ X,
    float* __restrict__ colsum, int N)
{
  __shared__ u16 Pl[128][264];
  const int tid = threadIdx.x;
  const int wave = tid >> 6, lane = tid & 63;
  const int lm = lane & 15, lq = lane >> 4;
  const int minrow = blockIdx.x * 128;
  int r0 = minrow;
  if (r0 > N - 128) r0 = N - 128;
  const int n0 = wave * 64;

  // stage 1: P cols [n0, n0+64)
  {
    f32x4 acc[8][4] = {};
    #pragma unroll
    for (int k0 = 0; k0 < 64; k0 += 32) {
      bf16x8 a[8], b[4];
      #pragma unroll
      for (int ct = 0; ct < 4; ++ct)
        b[ct] = *(const bf16x8*)(agg + (size_t)(n0 + ct * 16 + lm) * 64 + k0 + lq * 8);
      #pragma unroll
      for (int rt = 0; rt < 8; ++rt)
        a[rt] = *(const bf16x8*)(Wt + (size_t)(r0 + rt * 16 + lm) * 64 + k0 + lq * 8);
      #pragma unroll
      for (int rt = 0; rt < 8; ++rt)
        #pragma unroll
        for (int ct = 0; ct < 4; ++ct)
          acc[rt][ct] = __builtin_amdgcn_mfma_f32_16x16x32_bf16(a[rt], b[ct], acc[rt][ct], 0, 0, 0);
    }
    #pragma unroll
    for (int rt = 0; rt < 8; ++rt)
      #pragma unroll
      for (int ct = 0; ct < 4; ++ct)
        #pragma unroll
        for (int rg = 0; rg < 4; ++rg)
          Pl[rt * 16 + lq * 4 + rg][n0 + ct * 16 + lm] = f2b(gelu_f(acc[rt][ct][rg]));
  }
  __syncthreads();

  // stage 2: X = [P | Hfg] @ W2T + b, cols [n0, n0+64) per wave
  f32x4 acc[8][4] = {};
  #pragma unroll 2
  for (int k0 = 0; k0 < 256; k0 += 32) {
    bf16x8 a[8], b[4];
    #pragma unroll
    for (int ct = 0; ct < 4; ++ct)
      b[ct] = *(const bf16x8*)(W2T + (size_t)(n0 + ct * 16 + lm) * 512 + k0 + lq * 8);
    #pragma unroll
    for (int rt = 0; rt < 8; ++rt)
      a[rt] = *(const bf16x8*)&Pl[rt * 16 + lm][k0 + lq * 8];
    #pragma unroll
    for (int rt = 0; rt < 8; ++rt)
      #pragma unroll
      for (int ct = 0; ct < 4; ++ct)
        acc[rt][ct] = __builtin_amdgcn_mfma_f32_16x16x32_bf16(a[rt], b[ct], acc[rt][ct], 0, 0, 0);
  }
  #pragma unroll 2
  for (int k0 = 256; k0 < 512; k0 += 32) {
    bf16x8 a[8], b[4];
    #pragma unroll
    for (int ct = 0; ct < 4; ++ct)
      b[ct] = *(const bf16x8*)(W2T + (size_t)(n0 + ct * 16 + lm) * 512 + k0 + lq * 8);
    #pragma unroll
    for (int rt = 0; rt < 8; ++rt)
      a[rt] = *(const bf16x8*)(Hfg + (size_t)(r0 + rt * 16 + lm) * 256 + (k0 - 256) + lq * 8);
    #pragma unroll
    for (int rt = 0; rt < 8; ++rt)
      #pragma unroll
      for (int ct = 0; ct < 4; ++ct)
        acc[rt][ct] = __builtin_amdgcn_mfma_f32_16x16x32_bf16(a[rt], b[ct], acc[rt][ct], 0, 0, 0);
  }
  float bv[4];
  #pragma unroll
  for (int ct = 0; ct < 4; ++ct) bv[ct] = bias[n0 + ct * 16 + lm];
  if constexpr (!COLSUM) {
    #pragma unroll
    for (int rt = 0; rt < 8; ++rt)
      #pragma unroll
      for (int ct = 0; ct < 4; ++ct)
        #pragma unroll
        for (int rg = 0; rg < 4; ++rg)
          X[(size_t)(r0 + rt * 16 + lq * 4 + rg) * 256 + n0 + ct * 16 + lm] =
              f2b(acc[rt][ct][rg] + bv[ct]);
  } else {
    #pragma unroll
    for (int ct = 0; ct < 4; ++ct) {
      float cs = 0.0f;
      #pragma unroll
      for (int rt = 0; rt < 8; ++rt)
        #pragma unroll
        for (int rg = 0; rg < 4; ++rg) {
          int row = r0 + rt * 16 + lq * 4 + rg;
          if (row >= minrow) cs += acc[rt][ct][rg] + bv[ct];
        }
      cs += __shfl_down(cs, 32);
      cs += __shfl_down(cs, 16);
      if (lq == 0) atomicAdd(&colsum[n0 + ct * 16 + lm], cs);
    }
  }
}

__global__ __launch_bounds__(64) void head_kernel(
    const float* __restrict__ colsum, const float* __restrict__ head_w,
    const float* __restrict__ head_b, float* __restrict__ out, float invN)
{
  const int c = threadIdx.x;   // 64
  float s = head_b[c];
  for (int h = 0; h < 256; ++h) s = fmaf(colsum[h] * invN, head_w[h * 64 + c], s);
  out[c] = s;
}

// ---------------------------------------------------------------------------
extern "C" void kernel_launch(void* const* d_in, const int* in_sizes, int n_in,
                              void* d_out, int out_size, void* d_ws, size_t ws_size,
                              hipStream_t stream)
{
  const float* x        = (const float*)d_in[0];
  // d_in[1] = edge_index: unused by the reference
  const float* ff1_w[2] = {(const float*)d_in[2],  (const float*)d_in[8]};
  const float* ff1_b[2] = {(const float*)d_in[3],  (const float*)d_in[9]};
  const float* wA[2]    = {(const float*)d_in[4],  (const float*)d_in[10]};
  const float* wB[2]    = {(const float*)d_in[5],  (const float*)d_in[11]};
  const float* ff2_w[2] = {(const float*)d_in[6],  (const float*)d_in[12]};
  const float* ff2_b[2] = {(const float*)d_in[7],  (const float*)d_in[13]};
  const float* head_w   = (const float*)d_in[14];
  const float* head_b   = (const float*)d_in[15];
  const int N = in_sizes[0] / 256;   // 200000, divisible by 64

  char* ws = (char*)d_ws;
  u16* WT = (u16*)ws;                       // 557056 bf16 elements
  u16* W1T[2] = {WT + 0,      WT + 278528};
  u16* wAT[2] = {WT + 65536,  WT + 344064};
  u16* wBT[2] = {WT + 131072, WT + 409600};
  u16* W2T[2] = {WT + 147456, WT + 425984};
  size_t o = 1114112;                       // 557056*2 bytes, 256-aligned
  u16* Hf  = (u16*)(ws + o); o += (size_t)N * 256 * 2;   // gelu(FF1)
  u16* Hfg = (u16*)(ws + o); o += (size_t)N * 256 * 2;   // gelu(Hf) for concat
  u16* TX  = (u16*)(ws + o); o += (size_t)N * 256 * 2;   // X1 (block-0 output)
  u16* Wt  = (u16*)(ws + o); o += (size_t)N * 64 * 2;    // W_tar
  float* Spart  = (float*)(ws + o); o += (size_t)512 * 16384 * 4;
  u16*   agg    = (u16*)(ws + o);   o += 16384 * 2;
  float* colsum = (float*)(ws + o); o += 256 * 4;
  (void)ws_size; (void)n_in; (void)out_size;

  hipMemsetAsync(colsum, 0, 256 * sizeof(float), stream);
  prep_weights<<<2176, 256, 0, stream>>>(ff1_w[0], wA[0], wB[0], ff2_w[0],
                                         ff1_w[1], wA[1], wB[1], ff2_w[1], WT);
  const int G = (N + 127) / 128;   // 1563 (last block clamps r0 to N-128)
  // block 0
  ff1_v3<true><<<G, 256, 0, stream>>>(x, W1T[0], ff1_b[0], Hf, Hfg, N);
  hyper_v3<<<G, 256, 0, stream>>>(Hf, wAT[0], wBT[0], Wt, N);
  s_partial<<<512, 256, 0, stream>>>(Hf, Wt, Spart, N);
  s_reduce<<<64, 256, 0, stream>>>(Spart, agg, 512);
  fused_p_ff2_v4<false><<<G, 256, 0, stream>>>(Wt, agg, Hfg, W2T[0], ff2_b[0], TX, nullptr, N);
  // block 1
  ff1_v3<false><<<G, 256, 0, stream>>>(TX, W1T[1], ff1_b[1], Hf, Hfg, N);
  hyper_v3<<<G, 256, 0, stream>>>(Hf, wAT[1], wBT[1], Wt, N);
  s_partial<<<512, 256, 0, stream>>>(Hf, Wt, Spart, N);
  s_reduce<<<64, 256, 0, stream>>>(Spart, agg, 512);
  fused_p_ff2_v4<true><<<G, 256, 0, stream>>>(Wt, agg, Hfg, W2T[1], ff2_b[1], nullptr, colsum, N);
  head_kernel<<<1, 64, 0, stream>>>(colsum, head_w, head_b, (float*)d_out, 1.0f / (float)N);
}

// Round 4
// 1177.994 us; speedup vs baseline: 1.7584x; 1.2480x over previous
//
#include <hip/hip_runtime.h>

// GHM_68143951118654 — bf16 MFMA, v4: fast tanh-gelu (1 exp + 1 rcp),
// merged ff1+hyper mega-kernel (128-row), fused P/FF2 at 64-row tiles for
// occupancy, colsum fused in final FF2.

typedef unsigned short u16;
typedef unsigned int u32;
typedef short bf16x8 __attribute__((ext_vector_type(8)));
typedef float f32x4 __attribute__((ext_vector_type(4)));

// gelu(x) ~= x * sigmoid(1.5957691x + 0.0713549x^3), exp2-folded.
// max |err| vs exact erf-gelu ~3.5e-4 (below bf16 quantization noise here).
__device__ __forceinline__ float gelu_f(float x) {
  float s = x * x;
  float z = x * fmaf(s, -0.10294348f, -2.3022077f);   // -(log2e)*(c1 x^2 + c0)
  float e = __builtin_amdgcn_exp2f(z);
  return x * __builtin_amdgcn_rcpf(1.0f + e);
}
__device__ __forceinline__ u16 f2b(float f) {
  union { float f; unsigned u; } v; v.f = f;
  unsigned u = v.u;
  u += 0x7fffu + ((u >> 16) & 1u);   // round-to-nearest-even
  return (u16)(u >> 16);
}

// ---------------------------------------------------------------------------
// Weight prep: fp32 -> bf16, transposed to [out][in].
// ---------------------------------------------------------------------------
__global__ __launch_bounds__(256) void prep_weights(
    const float* __restrict__ s0, const float* __restrict__ s1,
    const float* __restrict__ s2, const float* __restrict__ s3,
    const float* __restrict__ s4, const float* __restrict__ s5,
    const float* __restrict__ s6, const float* __restrict__ s7,
    u16* __restrict__ dst)
{
  int idx = blockIdx.x * 256 + threadIdx.x;
  if (idx >= 557056) return;
  const float* src; int base, R, C;
  if (idx < 278528) {
    if (idx < 131072) {
      if (idx < 65536) { base = 0;      src = s0; R = 256; C = 256; }
      else             { base = 65536;  src = s1; R = 256; C = 256; }
    } else {
      if (idx < 147456){ base = 131072; src = s2; R = 256; C = 64;  }
      else             { base = 147456; src = s3; R = 512; C = 256; }
    }
  } else {
    int j = idx - 278528;
    if (j < 131072) {
      if (j < 65536)   { base = 278528; src = s4; R = 256; C = 256; }
      else             { base = 344064; src = s5; R = 256; C = 256; }
    } else {
      if (j < 147456)  { base = 409600; src = s6; R = 256; C = 64;  }
      else             { base = 425984; src = s7; R = 512; C = 256; }
    }
  }
  int local = idx - base;
  int o = local / R;
  int k = local - o * R;
  dst[idx] = f2b(src[k * C + o]);   // dst[o][k] = src[k][o]
}

// ---------------------------------------------------------------------------
// Mega: FF1 + hyper. 128 rows/block, 4 waves col-split.
//  X tile -> LDS; Hf = gelu(X@W1^T+b) -> global + LDS (+Hfg global);
//  T = gelu(Hf@wA^T) -> LDS; Wt = T@wB^T -> global.
// ---------------------------------------------------------------------------
template<bool AFP32>
__global__ __launch_bounds__(256, 2) void ff1_hyper(
    const void* __restrict__ Av, const u16* __restrict__ W1T,
    const float* __restrict__ bias, const u16* __restrict__ wAT,
    const u16* __restrict__ wBT, u16* __restrict__ Hf,
    u16* __restrict__ Hfg, u16* __restrict__ Wt, int N)
{
  __shared__ u16 Asm[128][264];
  const int tid = threadIdx.x;
  const int wave = tid >> 6, lane = tid & 63;
  int r0 = blockIdx.x * 128;
  if (r0 > N - 128) r0 = N - 128;

  if constexpr (AFP32) {
    const float* A = (const float*)Av;
    #pragma unroll
    for (int j = 0; j < 32; ++j) {
      int idx = j * 256 + tid;
      int row = idx >> 6, c4 = idx & 63;
      float4 v = *(const float4*)(A + (size_t)(r0 + row) * 256 + c4 * 4);
      uint2 p;
      p.x = (u32)f2b(v.x) | ((u32)f2b(v.y) << 16);
      p.y = (u32)f2b(v.z) | ((u32)f2b(v.w) << 16);
      *(uint2*)&Asm[row][c4 * 4] = p;
    }
  } else {
    const u16* A = (const u16*)Av;
    #pragma unroll
    for (int j = 0; j < 16; ++j) {
      int idx = j * 256 + tid;
      int row = idx >> 5, c8 = idx & 31;
      *(uint4*)&Asm[row][c8 * 8] =
          *(const uint4*)(A + (size_t)(r0 + row) * 256 + c8 * 8);
    }
  }
  __syncthreads();

  const int lm = lane & 15, lq = lane >> 4;
  const int n0 = wave * 64;

  // ---- FF1: acc = X @ W1^T (cols n0..n0+63) ----
  f32x4 acc[8][4] = {};
  #pragma unroll 2
  for (int k0 = 0; k0 < 256; k0 += 32) {
    bf16x8 a[8], b[4];
    #pragma unroll
    for (int ct = 0; ct < 4; ++ct)
      b[ct] = *(const bf16x8*)(W1T + (size_t)(n0 + ct * 16 + lm) * 256 + k0 + lq * 8);
    #pragma unroll
    for (int rt = 0; rt < 8; ++rt)
      a[rt] = *(const bf16x8*)&Asm[rt * 16 + lm][k0 + lq * 8];
    #pragma unroll
    for (int rt = 0; rt < 8; ++rt)
      #pragma unroll
      for (int ct = 0; ct < 4; ++ct)
        acc[rt][ct] = __builtin_amdgcn_mfma_f32_16x16x32_bf16(a[rt], b[ct], acc[rt][ct], 0, 0, 0);
  }
  __syncthreads();   // done reading X tile
  {
    float bv[4];
    #pragma unroll
    for (int ct = 0; ct < 4; ++ct) bv[ct] = bias[n0 + ct * 16 + lm];
    #pragma unroll
    for (int rt = 0; rt < 8; ++rt)
      #pragma unroll
      for (int ct = 0; ct < 4; ++ct)
        #pragma unroll
        for (int rg = 0; rg < 4; ++rg) {
          float g = gelu_f(acc[rt][ct][rg] + bv[ct]);
          u16 gb = f2b(g);
          int row = rt * 16 + lq * 4 + rg, col = n0 + ct * 16 + lm;
          size_t idx = (size_t)(r0 + row) * 256 + col;
          Hf[idx] = gb;
          Hfg[idx] = f2b(gelu_f(g));
          Asm[row][col] = gb;
        }
  }
  __syncthreads();

  // ---- T = gelu(Hf @ wA^T), cols n0..n0+63 ----
  #pragma unroll
  for (int rt = 0; rt < 8; ++rt)
    #pragma unroll
    for (int ct = 0; ct < 4; ++ct)
      acc[rt][ct] = (f32x4){0.f, 0.f, 0.f, 0.f};
  #pragma unroll 2
  for (int k0 = 0; k0 < 256; k0 += 32) {
    bf16x8 a[8], b[4];
    #pragma unroll
    for (int ct = 0; ct < 4; ++ct)
      b[ct] = *(const bf16x8*)(wAT + (size_t)(n0 + ct * 16 + lm) * 256 + k0 + lq * 8);
    #pragma unroll
    for (int rt = 0; rt < 8; ++rt)
      a[rt] = *(const bf16x8*)&Asm[rt * 16 + lm][k0 + lq * 8];
    #pragma unroll
    for (int rt = 0; rt < 8; ++rt)
      #pragma unroll
      for (int ct = 0; ct < 4; ++ct)
        acc[rt][ct] = __builtin_amdgcn_mfma_f32_16x16x32_bf16(a[rt], b[ct], acc[rt][ct], 0, 0, 0);
  }
  __syncthreads();   // done reading Hf tile
  #pragma unroll
  for (int rt = 0; rt < 8; ++rt)
    #pragma unroll
    for (int ct = 0; ct < 4; ++ct)
      #pragma unroll
      for (int rg = 0; rg < 4; ++rg)
        Asm[rt * 16 + lq * 4 + rg][n0 + ct * 16 + lm] = f2b(gelu_f(acc[rt][ct][rg]));
  __syncthreads();

  // ---- Wt = T @ wB^T: rows [32*wave, 32*wave+32), 64 cols ----
  f32x4 acc2[2][4] = {};
  #pragma unroll 2
  for (int k0 = 0; k0 < 256; k0 += 32) {
    bf16x8 a[2], b[4];
    #pragma unroll
    for (int ct = 0; ct < 4; ++ct)
      b[ct] = *(const bf16x8*)(wBT + (size_t)(ct * 16 + lm) * 256 + k0 + lq * 8);
    #pragma unroll
    for (int rt = 0; rt < 2; ++rt)
      a[rt] = *(const bf16x8*)&Asm[wave * 32 + rt * 16 + lm][k0 + lq * 8];
    #pragma unroll
    for (int rt = 0; rt < 2; ++rt)
      #pragma unroll
      for (int ct = 0; ct < 4; ++ct)
        acc2[rt][ct] = __builtin_amdgcn_mfma_f32_16x16x32_bf16(a[rt], b[ct], acc2[rt][ct], 0, 0, 0);
  }
  #pragma unroll
  for (int rt = 0; rt < 2; ++rt)
    #pragma unroll
    for (int ct = 0; ct < 4; ++ct)
      #pragma unroll
      for (int rg = 0; rg < 4; ++rg)
        Wt[(size_t)(r0 + wave * 32 + rt * 16 + lq * 4 + rg) * 64 + ct * 16 + lm] =
            f2b(acc2[rt][ct][rg]);
}

// ---------------------------------------------------------------------------
// S partials: S[h][m] = sum_i Hf[i][h]*Wt[i][m]. Pair-packed b32 transpose.
// ---------------------------------------------------------------------------
__global__ __launch_bounds__(256) void s_partial(
    const u16* __restrict__ Hf, const u16* __restrict__ Wt,
    float* __restrict__ Spart, int N)
{
  __shared__ u16 HfT[256][72];
  __shared__ u16 WtT[64][72];
  const int tid = threadIdx.x;
  const int wave = tid >> 6, lane = tid & 63;
  const int lm = lane & 15, lq = lane >> 4;
  const int rp = tid & 31;
  const int mb = tid >> 5;
  f32x4 acc[4][4] = {};
  const int nchunk = N >> 6;
  for (int ch = blockIdx.x; ch < nchunk; ch += gridDim.x) {
    const int i0 = ch << 6;
    __syncthreads();
    #pragma unroll
    for (int q = 0; q < 4; ++q) {
      int m = mb + 8 * q;
      const u16* px = Hf + (size_t)(i0 + 2 * rp) * 256 + m * 8;
      uint4 xv = *(const uint4*)px;
      uint4 yv = *(const uint4*)(px + 256);
      u32 xs[4] = {xv.x, xv.y, xv.z, xv.w};
      u32 ys[4] = {yv.x, yv.y, yv.z, yv.w};
      #pragma unroll
      for (int t = 0; t < 4; ++t) {
        *(u32*)&HfT[m * 8 + 2 * t][2 * rp]     = (xs[t] & 0xFFFFu) | (ys[t] << 16);
        *(u32*)&HfT[m * 8 + 2 * t + 1][2 * rp] = (xs[t] >> 16) | (ys[t] & 0xFFFF0000u);
      }
    }
    {
      const u16* px = Wt + (size_t)(i0 + 2 * rp) * 64 + mb * 8;
      uint4 xv = *(const uint4*)px;
      uint4 yv = *(const uint4*)(px + 64);
      u32 xs[4] = {xv.x, xv.y, xv.z, xv.w};
      u32 ys[4] = {yv.x, yv.y, yv.z, yv.w};
      #pragma unroll
      for (int t = 0; t < 4; ++t) {
        *(u32*)&WtT[mb * 8 + 2 * t][2 * rp]     = (xs[t] & 0xFFFFu) | (ys[t] << 16);
        *(u32*)&WtT[mb * 8 + 2 * t + 1][2 * rp] = (xs[t] >> 16) | (ys[t] & 0xFFFF0000u);
      }
    }
    __syncthreads();
    #pragma unroll
    for (int k0 = 0; k0 < 64; k0 += 32) {
      bf16x8 a[4], b[4];
      #pragma unroll
      for (int t = 0; t < 4; ++t)
        a[t] = *(const bf16x8*)&HfT[wave * 64 + t * 16 + lm][k0 + lq * 8];
      #pragma unroll
      for (int m = 0; m < 4; ++m)
        b[m] = *(const bf16x8*)&WtT[m * 16 + lm][k0 + lq * 8];
      #pragma unroll
      for (int t = 0; t < 4; ++t)
        #pragma unroll
        for (int m = 0; m < 4; ++m)
          acc[t][m] = __builtin_amdgcn_mfma_f32_16x16x32_bf16(a[t], b[m], acc[t][m], 0, 0, 0);
    }
  }
  float* out = Spart + (size_t)blockIdx.x * 16384;
  #pragma unroll
  for (int t = 0; t < 4; ++t)
    #pragma unroll
    for (int m = 0; m < 4; ++m)
      #pragma unroll
      for (int rg = 0; rg < 4; ++rg)
        out[(size_t)(wave * 64 + t * 16 + lq * 4 + rg) * 64 + m * 16 + lm] = acc[t][m][rg];
}

__global__ __launch_bounds__(256) void s_reduce(
    const float* __restrict__ Spart, u16* __restrict__ agg, int nparts)
{
  int e = blockIdx.x * 256 + threadIdx.x;
  float s0 = 0.f, s1 = 0.f, s2 = 0.f, s3 = 0.f;
  for (int p = 0; p < nparts; p += 4) {
    s0 += Spart[(size_t)(p + 0) * 16384 + e];
    s1 += Spart[(size_t)(p + 1) * 16384 + e];
    s2 += Spart[(size_t)(p + 2) * 16384 + e];
    s3 += Spart[(size_t)(p + 3) * 16384 + e];
  }
  agg[e] = f2b(gelu_f((s0 + s1) + (s2 + s3)));
}

// ---------------------------------------------------------------------------
// Fused: P = gelu(Wt @ agg^T) into LDS (64x256), then
// X = [P | gelu(Hf)] @ ff2^T + b. 64 rows/block, 4 waves col-split.
// COLSUM: column-sum instead of store.
// ---------------------------------------------------------------------------
template<bool COLSUM>
__global__ __launch_bounds__(256, 4) void fused_p_ff2_v5(
    const u16* __restrict__ Wt, const u16* __restrict__ agg,
    const u16* __restrict__ Hfg, const u16* __restrict__ W2T,
    const float* __restrict__ bias, u16* __restrict__ X,
    float* __restrict__ colsum, int N)
{
  __shared__ u16 Pl[64][264];
  const int tid = threadIdx.x;
  const int wave = tid >> 6, lane = tid & 63;
  const int lm = lane & 15, lq = lane >> 4;
  const int r0 = blockIdx.x * 64;   // N % 64 == 0
  const int n0 = wave * 64;

  // stage 1: P cols [n0, n0+64)
  {
    f32x4 acc[4][4] = {};
    #pragma unroll
    for (int k0 = 0; k0 < 64; k0 += 32) {
      bf16x8 a[4], b[4];
      #pragma unroll
      for (int ct = 0; ct < 4; ++ct)
        b[ct] = *(const bf16x8*)(agg + (size_t)(n0 + ct * 16 + lm) * 64 + k0 + lq * 8);
      #pragma unroll
      for (int rt = 0; rt < 4; ++rt)
        a[rt] = *(const bf16x8*)(Wt + (size_t)(r0 + rt * 16 + lm) * 64 + k0 + lq * 8);
      #pragma unroll
      for (int rt = 0; rt < 4; ++rt)
        #pragma unroll
        for (int ct = 0; ct < 4; ++ct)
          acc[rt][ct] = __builtin_amdgcn_mfma_f32_16x16x32_bf16(a[rt], b[ct], acc[rt][ct], 0, 0, 0);
    }
    #pragma unroll
    for (int rt = 0; rt < 4; ++rt)
      #pragma unroll
      for (int ct = 0; ct < 4; ++ct)
        #pragma unroll
        for (int rg = 0; rg < 4; ++rg)
          Pl[rt * 16 + lq * 4 + rg][n0 + ct * 16 + lm] = f2b(gelu_f(acc[rt][ct][rg]));
  }
  __syncthreads();

  // stage 2: X = [P | Hfg] @ W2T + b, cols [n0, n0+64)
  f32x4 acc[4][4] = {};
  #pragma unroll 2
  for (int k0 = 0; k0 < 256; k0 += 32) {
    bf16x8 a[4], b[4];
    #pragma unroll
    for (int ct = 0; ct < 4; ++ct)
      b[ct] = *(const bf16x8*)(W2T + (size_t)(n0 + ct * 16 + lm) * 512 + k0 + lq * 8);
    #pragma unroll
    for (int rt = 0; rt < 4; ++rt)
      a[rt] = *(const bf16x8*)&Pl[rt * 16 + lm][k0 + lq * 8];
    #pragma unroll
    for (int rt = 0; rt < 4; ++rt)
      #pragma unroll
      for (int ct = 0; ct < 4; ++ct)
        acc[rt][ct] = __builtin_amdgcn_mfma_f32_16x16x32_bf16(a[rt], b[ct], acc[rt][ct], 0, 0, 0);
  }
  #pragma unroll 2
  for (int k0 = 256; k0 < 512; k0 += 32) {
    bf16x8 a[4], b[4];
    #pragma unroll
    for (int ct = 0; ct < 4; ++ct)
      b[ct] = *(const bf16x8*)(W2T + (size_t)(n0 + ct * 16 + lm) * 512 + k0 + lq * 8);
    #pragma unroll
    for (int rt = 0; rt < 4; ++rt)
      a[rt] = *(const bf16x8*)(Hfg + (size_t)(r0 + rt * 16 + lm) * 256 + (k0 - 256) + lq * 8);
    #pragma unroll
    for (int rt = 0; rt < 4; ++rt)
      #pragma unroll
      for (int ct = 0; ct < 4; ++ct)
        acc[rt][ct] = __builtin_amdgcn_mfma_f32_16x16x32_bf16(a[rt], b[ct], acc[rt][ct], 0, 0, 0);
  }
  float bv[4];
  #pragma unroll
  for (int ct = 0; ct < 4; ++ct) bv[ct] = bias[n0 + ct * 16 + lm];
  if constexpr (!COLSUM) {
    #pragma unroll
    for (int rt = 0; rt < 4; ++rt)
      #pragma unroll
      for (int ct = 0; ct < 4; ++ct)
        #pragma unroll
        for (int rg = 0; rg < 4; ++rg)
          X[(size_t)(r0 + rt * 16 + lq * 4 + rg) * 256 + n0 + ct * 16 + lm] =
              f2b(acc[rt][ct][rg] + bv[ct]);
  } else {
    #pragma unroll
    for (int ct = 0; ct < 4; ++ct) {
      float cs = 0.0f;
      #pragma unroll
      for (int rt = 0; rt < 4; ++rt)
        #pragma unroll
        for (int rg = 0; rg < 4; ++rg) cs += acc[rt][ct][rg] + bv[ct];
      cs += __shfl_down(cs, 32);
      cs += __shfl_down(cs, 16);
      if (lq == 0) atomicAdd(&colsum[n0 + ct * 16 + lm], cs);
    }
  }
}

__global__ __launch_bounds__(64) void head_kernel(
    const float* __restrict__ colsum, const float* __restrict__ head_w,
    const float* __restrict__ head_b, float* __restrict__ out, float invN)
{
  const int c = threadIdx.x;
  float s = head_b[c];
  for (int h = 0; h < 256; ++h) s = fmaf(colsum[h] * invN, head_w[h * 64 + c], s);
  out[c] = s;
}

// ---------------------------------------------------------------------------
extern "C" void kernel_launch(void* const* d_in, const int* in_sizes, int n_in,
                              void* d_out, int out_size, void* d_ws, size_t ws_size,
                              hipStream_t stream)
{
  const float* x        = (const float*)d_in[0];
  const float* ff1_w[2] = {(const float*)d_in[2],  (const float*)d_in[8]};
  const float* ff1_b[2] = {(const float*)d_in[3],  (const float*)d_in[9]};
  const float* wA[2]    = {(const float*)d_in[4],  (const float*)d_in[10]};
  const float* wB[2]    = {(const float*)d_in[5],  (const float*)d_in[11]};
  const float* ff2_w[2] = {(const float*)d_in[6],  (const float*)d_in[12]};
  const float* ff2_b[2] = {(const float*)d_in[7],  (const float*)d_in[13]};
  const float* head_w   = (const float*)d_in[14];
  const float* head_b   = (const float*)d_in[15];
  const int N = in_sizes[0] / 256;   // 200000

  char* ws = (char*)d_ws;
  u16* WT = (u16*)ws;
  u16* W1T[2] = {WT + 0,      WT + 278528};
  u16* wAT[2] = {WT + 65536,  WT + 344064};
  u16* wBT[2] = {WT + 131072, WT + 409600};
  u16* W2T[2] = {WT + 147456, WT + 425984};
  size_t o = 1114112;
  u16* Hf  = (u16*)(ws + o); o += (size_t)N * 256 * 2;
  u16* Hfg = (u16*)(ws + o); o += (size_t)N * 256 * 2;
  u16* TX  = (u16*)(ws + o); o += (size_t)N * 256 * 2;
  u16* Wt  = (u16*)(ws + o); o += (size_t)N * 64 * 2;
  float* Spart  = (float*)(ws + o); o += (size_t)512 * 16384 * 4;
  u16*   agg    = (u16*)(ws + o);   o += 16384 * 2;
  float* colsum = (float*)(ws + o); o += 256 * 4;
  (void)ws_size; (void)n_in; (void)out_size;

  hipMemsetAsync(colsum, 0, 256 * sizeof(float), stream);
  prep_weights<<<2176, 256, 0, stream>>>(ff1_w[0], wA[0], wB[0], ff2_w[0],
                                         ff1_w[1], wA[1], wB[1], ff2_w[1], WT);
  const int G128 = (N + 127) / 128;   // 1563 (last block clamps r0)
  const int G64  = N / 64;            // 3125
  // block 0
  ff1_hyper<true><<<G128, 256, 0, stream>>>(x, W1T[0], ff1_b[0], wAT[0], wBT[0], Hf, Hfg, Wt, N);
  s_partial<<<512, 256, 0, stream>>>(Hf, Wt, Spart, N);
  s_reduce<<<64, 256, 0, stream>>>(Spart, agg, 512);
  fused_p_ff2_v5<false><<<G64, 256, 0, stream>>>(Wt, agg, Hfg, W2T[0], ff2_b[0], TX, nullptr, N);
  // block 1
  ff1_hyper<false><<<G128, 256, 0, stream>>>(TX, W1T[1], ff1_b[1], wAT[1], wBT[1], Hf, Hfg, Wt, N);
  s_partial<<<512, 256, 0, stream>>>(Hf, Wt, Spart, N);
  s_reduce<<<64, 256, 0, stream>>>(Spart, agg, 512);
  fused_p_ff2_v5<true><<<G64, 256, 0, stream>>>(Wt, agg, Hfg, W2T[1], ff2_b[1], nullptr, colsum, N);
  head_kernel<<<1, 64, 0, stream>>>(colsum, head_w, head_b, (float*)d_out, 1.0f / (float)N);
}

// Round 5
// 1077.435 us; speedup vs baseline: 1.9225x; 1.0933x over previous
//
#include <hip/hip_runtime.h>

// GHM_68143951118654 — bf16 MFMA, v5: fused kernel gets async global_load_lds
// staging of the Hfg tile (XOR-swizzled LDS) + fully-unrolled stage2 with
// register double-buffered frag prefetch; s_partial software-pipelined;
// ff1_hyper B-frag prefetch. Fast tanh-gelu throughout.

typedef unsigned short u16;
typedef unsigned int u32;
typedef short bf16x8 __attribute__((ext_vector_type(8)));
typedef float f32x4 __attribute__((ext_vector_type(4)));

__device__ __forceinline__ float gelu_f(float x) {
  float s = x * x;
  float z = x * fmaf(s, -0.10294348f, -2.3022077f);   // -(log2e)*(c1 x^2 + c0)
  float e = __builtin_amdgcn_exp2f(z);
  return x * __builtin_amdgcn_rcpf(1.0f + e);
}
__device__ __forceinline__ u16 f2b(float f) {
  union { float f; unsigned u; } v; v.f = f;
  unsigned u = v.u;
  u += 0x7fffu + ((u >> 16) & 1u);   // round-to-nearest-even
  return (u16)(u >> 16);
}
// XOR-swizzled 64xK tile offset (u16 elements): row-major 256/row, the 16B
// unit index has its low 3 bits XORed with (row&7) -> b128 reads are ~2-way.
__device__ __forceinline__ int swz(int row, int col) {
  return row * 256 + (((col >> 3) ^ (row & 7)) << 3) + (col & 7);
}

// ---------------------------------------------------------------------------
// Weight prep: fp32 -> bf16, transposed to [out][in].
// ---------------------------------------------------------------------------
__global__ __launch_bounds__(256) void prep_weights(
    const float* __restrict__ s0, const float* __restrict__ s1,
    const float* __restrict__ s2, const float* __restrict__ s3,
    const float* __restrict__ s4, const float* __restrict__ s5,
    const float* __restrict__ s6, const float* __restrict__ s7,
    u16* __restrict__ dst)
{
  int idx = blockIdx.x * 256 + threadIdx.x;
  if (idx >= 557056) return;
  const float* src; int base, R, C;
  if (idx < 278528) {
    if (idx < 131072) {
      if (idx < 65536) { base = 0;      src = s0; R = 256; C = 256; }
      else             { base = 65536;  src = s1; R = 256; C = 256; }
    } else {
      if (idx < 147456){ base = 131072; src = s2; R = 256; C = 64;  }
      else             { base = 147456; src = s3; R = 512; C = 256; }
    }
  } else {
    int j = idx - 278528;
    if (j < 131072) {
      if (j < 65536)   { base = 278528; src = s4; R = 256; C = 256; }
      else             { base = 344064; src = s5; R = 256; C = 256; }
    } else {
      if (j < 147456)  { base = 409600; src = s6; R = 256; C = 64;  }
      else             { base = 425984; src = s7; R = 512; C = 256; }
    }
  }
  int local = idx - base;
  int o = local / R;
  int k = local - o * R;
  dst[idx] = f2b(src[k * C + o]);   // dst[o][k] = src[k][o]
}

// ---------------------------------------------------------------------------
// Mega: FF1 + hyper. 128 rows/block, 4 waves col-split, B-frag prefetch.
// ---------------------------------------------------------------------------
template<bool AFP32>
__global__ __launch_bounds__(256, 2) void ff1_hyper(
    const void* __restrict__ Av, const u16* __restrict__ W1T,
    const float* __restrict__ bias, const u16* __restrict__ wAT,
    const u16* __restrict__ wBT, u16* __restrict__ Hf,
    u16* __restrict__ Hfg, u16* __restrict__ Wt, int N)
{
  __shared__ u16 Asm[128][264];
  const int tid = threadIdx.x;
  const int wave = tid >> 6, lane = tid & 63;
  int r0 = blockIdx.x * 128;
  if (r0 > N - 128) r0 = N - 128;

  if constexpr (AFP32) {
    const float* A = (const float*)Av;
    #pragma unroll
    for (int j = 0; j < 32; ++j) {
      int idx = j * 256 + tid;
      int row = idx >> 6, c4 = idx & 63;
      float4 v = *(const float4*)(A + (size_t)(r0 + row) * 256 + c4 * 4);
      uint2 p;
      p.x = (u32)f2b(v.x) | ((u32)f2b(v.y) << 16);
      p.y = (u32)f2b(v.z) | ((u32)f2b(v.w) << 16);
      *(uint2*)&Asm[row][c4 * 4] = p;
    }
  } else {
    const u16* A = (const u16*)Av;
    #pragma unroll
    for (int j = 0; j < 16; ++j) {
      int idx = j * 256 + tid;
      int row = idx >> 5, c8 = idx & 31;
      *(uint4*)&Asm[row][c8 * 8] =
          *(const uint4*)(A + (size_t)(r0 + row) * 256 + c8 * 8);
    }
  }
  __syncthreads();

  const int lm = lane & 15, lq = lane >> 4;
  const int n0 = wave * 64;

  // ---- FF1: acc = X @ W1^T (cols n0..n0+63), b prefetched ----
  f32x4 acc[8][4] = {};
  {
    bf16x8 bb[2][4];
    #pragma unroll
    for (int ct = 0; ct < 4; ++ct)
      bb[0][ct] = *(const bf16x8*)(W1T + (size_t)(n0 + ct * 16 + lm) * 256 + lq * 8);
    #pragma unroll
    for (int s = 0; s < 8; ++s) {
      const int cur = s & 1;
      if (s < 7)
        #pragma unroll
        for (int ct = 0; ct < 4; ++ct)
          bb[cur ^ 1][ct] = *(const bf16x8*)(W1T + (size_t)(n0 + ct * 16 + lm) * 256 + (s + 1) * 32 + lq * 8);
      bf16x8 a[8];
      #pragma unroll
      for (int rt = 0; rt < 8; ++rt)
        a[rt] = *(const bf16x8*)&Asm[rt * 16 + lm][s * 32 + lq * 8];
      #pragma unroll
      for (int rt = 0; rt < 8; ++rt)
        #pragma unroll
        for (int ct = 0; ct < 4; ++ct)
          acc[rt][ct] = __builtin_amdgcn_mfma_f32_16x16x32_bf16(a[rt], bb[cur][ct], acc[rt][ct], 0, 0, 0);
    }
  }
  __syncthreads();   // done reading X tile
  {
    float bv[4];
    #pragma unroll
    for (int ct = 0; ct < 4; ++ct) bv[ct] = bias[n0 + ct * 16 + lm];
    #pragma unroll
    for (int rt = 0; rt < 8; ++rt)
      #pragma unroll
      for (int ct = 0; ct < 4; ++ct)
        #pragma unroll
        for (int rg = 0; rg < 4; ++rg) {
          float g = gelu_f(acc[rt][ct][rg] + bv[ct]);
          u16 gb = f2b(g);
          int row = rt * 16 + lq * 4 + rg, col = n0 + ct * 16 + lm;
          size_t idx = (size_t)(r0 + row) * 256 + col;
          Hf[idx] = gb;
          Hfg[idx] = f2b(gelu_f(g));
          Asm[row][col] = gb;
        }
  }
  __syncthreads();

  // ---- T = gelu(Hf @ wA^T), b prefetched ----
  #pragma unroll
  for (int rt = 0; rt < 8; ++rt)
    #pragma unroll
    for (int ct = 0; ct < 4; ++ct)
      acc[rt][ct] = (f32x4){0.f, 0.f, 0.f, 0.f};
  {
    bf16x8 bb[2][4];
    #pragma unroll
    for (int ct = 0; ct < 4; ++ct)
      bb[0][ct] = *(const bf16x8*)(wAT + (size_t)(n0 + ct * 16 + lm) * 256 + lq * 8);
    #pragma unroll
    for (int s = 0; s < 8; ++s) {
      const int cur = s & 1;
      if (s < 7)
        #pragma unroll
        for (int ct = 0; ct < 4; ++ct)
          bb[cur ^ 1][ct] = *(const bf16x8*)(wAT + (size_t)(n0 + ct * 16 + lm) * 256 + (s + 1) * 32 + lq * 8);
      bf16x8 a[8];
      #pragma unroll
      for (int rt = 0; rt < 8; ++rt)
        a[rt] = *(const bf16x8*)&Asm[rt * 16 + lm][s * 32 + lq * 8];
      #pragma unroll
      for (int rt = 0; rt < 8; ++rt)
        #pragma unroll
        for (int ct = 0; ct < 4; ++ct)
          acc[rt][ct] = __builtin_amdgcn_mfma_f32_16x16x32_bf16(a[rt], bb[cur][ct], acc[rt][ct], 0, 0, 0);
    }
  }
  __syncthreads();   // done reading Hf tile
  #pragma unroll
  for (int rt = 0; rt < 8; ++rt)
    #pragma unroll
    for (int ct = 0; ct < 4; ++ct)
      #pragma unroll
      for (int rg = 0; rg < 4; ++rg)
        Asm[rt * 16 + lq * 4 + rg][n0 + ct * 16 + lm] = f2b(gelu_f(acc[rt][ct][rg]));
  __syncthreads();

  // ---- Wt = T @ wB^T: rows [32*wave, +32), b prefetched ----
  f32x4 acc2[2][4] = {};
  {
    bf16x8 bb[2][4];
    #pragma unroll
    for (int ct = 0; ct < 4; ++ct)
      bb[0][ct] = *(const bf16x8*)(wBT + (size_t)(ct * 16 + lm) * 256 + lq * 8);
    #pragma unroll
    for (int s = 0; s < 8; ++s) {
      const int cur = s & 1;
      if (s < 7)
        #pragma unroll
        for (int ct = 0; ct < 4; ++ct)
          bb[cur ^ 1][ct] = *(const bf16x8*)(wBT + (size_t)(ct * 16 + lm) * 256 + (s + 1) * 32 + lq * 8);
      bf16x8 a[2];
      #pragma unroll
      for (int rt = 0; rt < 2; ++rt)
        a[rt] = *(const bf16x8*)&Asm[wave * 32 + rt * 16 + lm][s * 32 + lq * 8];
      #pragma unroll
      for (int rt = 0; rt < 2; ++rt)
        #pragma unroll
        for (int ct = 0; ct < 4; ++ct)
          acc2[rt][ct] = __builtin_amdgcn_mfma_f32_16x16x32_bf16(a[rt], bb[cur][ct], acc2[rt][ct], 0, 0, 0);
    }
  }
  #pragma unroll
  for (int rt = 0; rt < 2; ++rt)
    #pragma unroll
    for (int ct = 0; ct < 4; ++ct)
      #pragma unroll
      for (int rg = 0; rg < 4; ++rg)
        Wt[(size_t)(r0 + wave * 32 + rt * 16 + lq * 4 + rg) * 64 + ct * 16 + lm] =
            f2b(acc2[rt][ct][rg]);
}

// ---------------------------------------------------------------------------
// S partials, software-pipelined: chunk ch+1's global loads issue before the
// MFMA of chunk ch, so HBM latency hides behind MFMA + barrier.
// ---------------------------------------------------------------------------
__global__ __launch_bounds__(256) void s_partial_v2(
    const u16* __restrict__ Hf, const u16* __restrict__ Wt,
    float* __restrict__ Spart, int N)
{
  __shared__ u16 HfT[256][72];
  __shared__ u16 WtT[64][72];
  const int tid = threadIdx.x;
  const int wave = tid >> 6, lane = tid & 63;
  const int lm = lane & 15, lq = lane >> 4;
  const int rp = tid & 31;
  const int mb = tid >> 5;
  uint4 hx[4][2], wx[2];
  auto issue = [&](int ch) {
    int i0 = ch << 6;
    #pragma unroll
    for (int q = 0; q < 4; ++q) {
      const u16* px = Hf + (size_t)(i0 + 2 * rp) * 256 + (mb + 8 * q) * 8;
      hx[q][0] = *(const uint4*)px;
      hx[q][1] = *(const uint4*)(px + 256);
    }
    const u16* pw = Wt + (size_t)(i0 + 2 * rp) * 64 + mb * 8;
    wx[0] = *(const uint4*)pw;
    wx[1] = *(const uint4*)(pw + 64);
  };
  f32x4 acc[4][4] = {};
  const int nchunk = N >> 6;
  int ch = blockIdx.x;
  if (ch < nchunk) issue(ch);
  for (; ch < nchunk; ch += gridDim.x) {
    __syncthreads();   // prior MFMA done reading LDS
    #pragma unroll
    for (int q = 0; q < 4; ++q) {
      int m = mb + 8 * q;
      u32 xs[4] = {hx[q][0].x, hx[q][0].y, hx[q][0].z, hx[q][0].w};
      u32 ys[4] = {hx[q][1].x, hx[q][1].y, hx[q][1].z, hx[q][1].w};
      #pragma unroll
      for (int t = 0; t < 4; ++t) {
        *(u32*)&HfT[m * 8 + 2 * t][2 * rp]     = (xs[t] & 0xFFFFu) | (ys[t] << 16);
        *(u32*)&HfT[m * 8 + 2 * t + 1][2 * rp] = (xs[t] >> 16) | (ys[t] & 0xFFFF0000u);
      }
    }
    {
      u32 xs[4] = {wx[0].x, wx[0].y, wx[0].z, wx[0].w};
      u32 ys[4] = {wx[1].x, wx[1].y, wx[1].z, wx[1].w};
      #pragma unroll
      for (int t = 0; t < 4; ++t) {
        *(u32*)&WtT[mb * 8 + 2 * t][2 * rp]     = (xs[t] & 0xFFFFu) | (ys[t] << 16);
        *(u32*)&WtT[mb * 8 + 2 * t + 1][2 * rp] = (xs[t] >> 16) | (ys[t] & 0xFFFF0000u);
      }
    }
    __syncthreads();
    if (ch + (int)gridDim.x < nchunk) issue(ch + (int)gridDim.x);
    #pragma unroll
    for (int k0 = 0; k0 < 64; k0 += 32) {
      bf16x8 a[4], b[4];
      #pragma unroll
      for (int t = 0; t < 4; ++t)
        a[t] = *(const bf16x8*)&HfT[wave * 64 + t * 16 + lm][k0 + lq * 8];
      #pragma unroll
      for (int m = 0; m < 4; ++m)
        b[m] = *(const bf16x8*)&WtT[m * 16 + lm][k0 + lq * 8];
      #pragma unroll
      for (int t = 0; t < 4; ++t)
        #pragma unroll
        for (int m = 0; m < 4; ++m)
          acc[t][m] = __builtin_amdgcn_mfma_f32_16x16x32_bf16(a[t], b[m], acc[t][m], 0, 0, 0);
    }
  }
  float* out = Spart + (size_t)blockIdx.x * 16384;
  #pragma unroll
  for (int t = 0; t < 4; ++t)
    #pragma unroll
    for (int m = 0; m < 4; ++m)
      #pragma unroll
      for (int rg = 0; rg < 4; ++rg)
        out[(size_t)(wave * 64 + t * 16 + lq * 4 + rg) * 64 + m * 16 + lm] = acc[t][m][rg];
}

__global__ __launch_bounds__(256) void s_reduce(
    const float* __restrict__ Spart, u16* __restrict__ agg, int nparts)
{
  int e = blockIdx.x * 256 + threadIdx.x;
  float s0 = 0.f, s1 = 0.f, s2 = 0.f, s3 = 0.f;
  for (int p = 0; p < nparts; p += 4) {
    s0 += Spart[(size_t)(p + 0) * 16384 + e];
    s1 += Spart[(size_t)(p + 1) * 16384 + e];
    s2 += Spart[(size_t)(p + 2) * 16384 + e];
    s3 += Spart[(size_t)(p + 3) * 16384 + e];
  }
  agg[e] = f2b(gelu_f((s0 + s1) + (s2 + s3)));
}

// ---------------------------------------------------------------------------
// Fused: async global_load_lds stages the 64x256 Hfg tile (swizzled LDS);
// stage1 P = gelu(Wt@agg^T) -> swizzled LDS; stage2 fully-unrolled K=512 with
// double-buffered register frags (A from LDS, B from L2-resident W2T).
// ---------------------------------------------------------------------------
template<bool COLSUM>
__global__ __launch_bounds__(256, 2) void fused_p_ff2_v6(
    const u16* __restrict__ Wt, const u16* __restrict__ agg,
    const u16* __restrict__ Hfg, const u16* __restrict__ W2T,
    const float* __restrict__ bias, u16* __restrict__ X,
    float* __restrict__ colsum, int N)
{
  __shared__ u16 Hsm[64 * 256];   // swizzled gelu(Hf) tile (32 KB)
  __shared__ u16 Pl[64 * 256];    // swizzled P tile (32 KB)
  const int tid = threadIdx.x;
  const int wave = tid >> 6, lane = tid & 63;
  const int lm = lane & 15, lq = lane >> 4;
  const int r0 = blockIdx.x * 64;   // N % 64 == 0
  const int n0 = wave * 64;

  // async stage Hfg tile -> LDS, 8 x 1KB per wave, swizzle-consistent
  #pragma unroll
  for (int t = 0; t < 8; ++t) {
    int unit = (wave * 8 + t) * 64 + lane;   // 16B units, row-major swizzled
    int row = unit >> 5, ksw = unit & 31;
    int kc = ksw ^ (row & 7);
    const u16* g = Hfg + (size_t)(r0 + row) * 256 + kc * 8;
    __builtin_amdgcn_global_load_lds(
        (const __attribute__((address_space(1))) void*)g,
        (__attribute__((address_space(3))) void*)(Hsm + (size_t)(wave * 8 + t) * 512),
        16, 0, 0);
  }

  // stage 1: P cols [n0, n0+64) -> swizzled Pl
  {
    f32x4 acc[4][4] = {};
    #pragma unroll
    for (int k0 = 0; k0 < 64; k0 += 32) {
      bf16x8 a[4], b[4];
      #pragma unroll
      for (int ct = 0; ct < 4; ++ct)
        b[ct] = *(const bf16x8*)(agg + (size_t)(n0 + ct * 16 + lm) * 64 + k0 + lq * 8);
      #pragma unroll
      for (int rt = 0; rt < 4; ++rt)
        a[rt] = *(const bf16x8*)(Wt + (size_t)(r0 + rt * 16 + lm) * 64 + k0 + lq * 8);
      #pragma unroll
      for (int rt = 0; rt < 4; ++rt)
        #pragma unroll
        for (int ct = 0; ct < 4; ++ct)
          acc[rt][ct] = __builtin_amdgcn_mfma_f32_16x16x32_bf16(a[rt], b[ct], acc[rt][ct], 0, 0, 0);
    }
    #pragma unroll
    for (int rt = 0; rt < 4; ++rt)
      #pragma unroll
      for (int ct = 0; ct < 4; ++ct)
        #pragma unroll
        for (int rg = 0; rg < 4; ++rg)
          Pl[swz(rt * 16 + lq * 4 + rg, n0 + ct * 16 + lm)] = f2b(gelu_f(acc[rt][ct][rg]));
  }
  __syncthreads();   // drains global_load_lds too

  // stage 2: X = [P | Hfg] @ W2T + b, fully unrolled, double-buffered frags
  auto ldb = [&](int s, bf16x8* b) {
    #pragma unroll
    for (int ct = 0; ct < 4; ++ct)
      b[ct] = *(const bf16x8*)(W2T + (size_t)(n0 + ct * 16 + lm) * 512 + s * 32 + lq * 8);
  };
  auto lda = [&](int s, bf16x8* a) {
    const u16* base = (s < 8) ? Pl : Hsm;
    const int k0 = (s & 7) * 32;
    #pragma unroll
    for (int rt = 0; rt < 4; ++rt) {
      int row = rt * 16 + lm;
      a[rt] = *(const bf16x8*)&base[swz(row, k0 + lq * 8)];
    }
  };
  f32x4 acc[4][4] = {};
  bf16x8 ab[2][4], bb[2][4];
  ldb(0, bb[0]);
  lda(0, ab[0]);
  #pragma unroll
  for (int s = 0; s < 16; ++s) {
    const int cur = s & 1, nxt = cur ^ 1;
    if (s < 15) { ldb(s + 1, bb[nxt]); lda(s + 1, ab[nxt]); }
    #pragma unroll
    for (int rt = 0; rt < 4; ++rt)
      #pragma unroll
      for (int ct = 0; ct < 4; ++ct)
        acc[rt][ct] = __builtin_amdgcn_mfma_f32_16x16x32_bf16(ab[cur][rt], bb[cur][ct], acc[rt][ct], 0, 0, 0);
  }
  float bv[4];
  #pragma unroll
  for (int ct = 0; ct < 4; ++ct) bv[ct] = bias[n0 + ct * 16 + lm];
  if constexpr (!COLSUM) {
    #pragma unroll
    for (int rt = 0; rt < 4; ++rt)
      #pragma unroll
      for (int ct = 0; ct < 4; ++ct)
        #pragma unroll
        for (int rg = 0; rg < 4; ++rg)
          X[(size_t)(r0 + rt * 16 + lq * 4 + rg) * 256 + n0 + ct * 16 + lm] =
              f2b(acc[rt][ct][rg] + bv[ct]);
  } else {
    #pragma unroll
    for (int ct = 0; ct < 4; ++ct) {
      float cs = 0.0f;
      #pragma unroll
      for (int rt = 0; rt < 4; ++rt)
        #pragma unroll
        for (int rg = 0; rg < 4; ++rg) cs += acc[rt][ct][rg] + bv[ct];
      cs += __shfl_down(cs, 32);
      cs += __shfl_down(cs, 16);
      if (lq == 0) atomicAdd(&colsum[n0 + ct * 16 + lm], cs);
    }
  }
}

__global__ __launch_bounds__(64) void head_kernel(
    const float* __restrict__ colsum, const float* __restrict__ head_w,
    const float* __restrict__ head_b, float* __restrict__ out, float invN)
{
  const int c = threadIdx.x;
  float s = head_b[c];
  for (int h = 0; h < 256; ++h) s = fmaf(colsum[h] * invN, head_w[h * 64 + c], s);
  out[c] = s;
}

// ---------------------------------------------------------------------------
extern "C" void kernel_launch(void* const* d_in, const int* in_sizes, int n_in,
                              void* d_out, int out_size, void* d_ws, size_t ws_size,
                              hipStream_t stream)
{
  const float* x        = (const float*)d_in[0];
  const float* ff1_w[2] = {(const float*)d_in[2],  (const float*)d_in[8]};
  const float* ff1_b[2] = {(const float*)d_in[3],  (const float*)d_in[9]};
  const float* wA[2]    = {(const float*)d_in[4],  (const float*)d_in[10]};
  const float* wB[2]    = {(const float*)d_in[5],  (const float*)d_in[11]};
  const float* ff2_w[2] = {(const float*)d_in[6],  (const float*)d_in[12]};
  const float* ff2_b[2] = {(const float*)d_in[7],  (const float*)d_in[13]};
  const float* head_w   = (const float*)d_in[14];
  const float* head_b   = (const float*)d_in[15];
  const int N = in_sizes[0] / 256;   // 200000

  char* ws = (char*)d_ws;
  u16* WT = (u16*)ws;
  u16* W1T[2] = {WT + 0,      WT + 278528};
  u16* wAT[2] = {WT + 65536,  WT + 344064};
  u16* wBT[2] = {WT + 131072, WT + 409600};
  u16* W2T[2] = {WT + 147456, WT + 425984};
  size_t o = 1114112;
  u16* Hf  = (u16*)(ws + o); o += (size_t)N * 256 * 2;
  u16* Hfg = (u16*)(ws + o); o += (size_t)N * 256 * 2;
  u16* TX  = (u16*)(ws + o); o += (size_t)N * 256 * 2;
  u16* Wt  = (u16*)(ws + o); o += (size_t)N * 64 * 2;
  float* Spart  = (float*)(ws + o); o += (size_t)512 * 16384 * 4;
  u16*   agg    = (u16*)(ws + o);   o += 16384 * 2;
  float* colsum = (float*)(ws + o); o += 256 * 4;
  (void)ws_size; (void)n_in; (void)out_size;

  hipMemsetAsync(colsum, 0, 256 * sizeof(float), stream);
  prep_weights<<<2176, 256, 0, stream>>>(ff1_w[0], wA[0], wB[0], ff2_w[0],
                                         ff1_w[1], wA[1], wB[1], ff2_w[1], WT);
  const int G128 = (N + 127) / 128;   // last block clamps r0
  const int G64  = N / 64;
  // block 0
  ff1_hyper<true><<<G128, 256, 0, stream>>>(x, W1T[0], ff1_b[0], wAT[0], wBT[0], Hf, Hfg, Wt, N);
  s_partial_v2<<<512, 256, 0, stream>>>(Hf, Wt, Spart, N);
  s_reduce<<<64, 256, 0, stream>>>(Spart, agg, 512);
  fused_p_ff2_v6<false><<<G64, 256, 0, stream>>>(Wt, agg, Hfg, W2T[0], ff2_b[0], TX, nullptr, N);
  // block 1
  ff1_hyper<false><<<G128, 256, 0, stream>>>(TX, W1T[1], ff1_b[1], wAT[1], wBT[1], Hf, Hfg, Wt, N);
  s_partial_v2<<<512, 256, 0, stream>>>(Hf, Wt, Spart, N);
  s_reduce<<<64, 256, 0, stream>>>(Spart, agg, 512);
  fused_p_ff2_v6<true><<<G64, 256, 0, stream>>>(Wt, agg, Hfg, W2T[1], ff2_b[1], nullptr, colsum, N);
  head_kernel<<<1, 64, 0, stream>>>(colsum, head_w, head_b, (float*)d_out, 1.0f / (float)N);
}